// Round 13
// baseline (194.315 us; speedup 1.0000x reference)
//
#include <hip/hip_runtime.h>
#include <math.h>

typedef unsigned short ushort_t;
typedef short bf16x8 __attribute__((ext_vector_type(8)));
typedef float f32x4 __attribute__((ext_vector_type(4)));
typedef unsigned short u16x8 __attribute__((ext_vector_type(8)));

#define S_ 128
#define B_ 64
#define W_ 16
#define CE_ 30
#define FN_ 4
#define WE_ 300
#define FEAT_ 420
#define C_ 512
#define NT_ 20
#define KL_ 448          // padded K for the 420->512 linear

#define LOG2E_ 1.44269504088896340736f
#define LN2_   0.69314718055994530942f

// ---- workspace layout (float units) ----
#define EM_OFF   0                       // 163,840 floats
#define NLL_OFF  163840                  // 64
#define H0_OFF   163968                  // each h buffer: 64*130*512 bf16 = 2,129,920 floats
#define HBUF_F   2129920
#define H1_OFF   (H0_OFF + HBUF_F)
#define WS_OFF   (H1_OFF + HBUF_F)       // conv w bf16: 3*1024*1536 = 2,359,296 floats
#define WSP_F    2359296
#define LW_OFF   (WS_OFF + WSP_F)        // lin_w bf16: 512*448 = 114,688 floats
#define FS_OFF   (LW_OFF + 114688)       // wf bf16: 8192*448 = 1,835,008 floats
#define FW_OFF   (FS_OFF + 1835008)      // fc_w transposed [20][512] fp32 = 10,240 floats
#define WLAYER   (1024*1536)             // ushort elems per layer

__device__ __forceinline__ float b2f(ushort_t h) {
    unsigned u = ((unsigned)h) << 16;
    float f; __builtin_memcpy(&f, &u, 4); return f;
}
__device__ __forceinline__ ushort_t f2b(float f) {   // round-to-nearest-even
    unsigned u; __builtin_memcpy(&u, &f, 4);
    unsigned r = (u + 0x7FFFu + ((u >> 16) & 1u)) >> 16;
    return (ushort_t)r;
}
__device__ __forceinline__ void gload16(const void* g, void* l) {
    __builtin_amdgcn_global_load_lds((const __attribute__((address_space(1))) void*)g,
                                     (__attribute__((address_space(3))) void*)l,
                                     16, 0, 0);
}

// ---------------- K1a: word embedding gather -> fsp bf16 cols 0..299 -------
__global__ void k_word_gather(const int* __restrict__ words,
                              const float* __restrict__ word_emb,
                              ushort_t* __restrict__ Fh) {
    int n = blockIdx.x;                  // n = s*B + b
    int s = n >> 6, b = n & 63;
    int np = b * 128 + s;
    int wid = words[n];
    int t = threadIdx.x;
    if (t < WE_ / 4) {
        float4 v = ((const float4*)(word_emb + (size_t)wid * WE_))[t];
        ushort4 o;
        o.x = f2b(v.x); o.y = f2b(v.y); o.z = f2b(v.z); o.w = f2b(v.w);
        *(ushort4*)(Fh + (size_t)np * KL_ + t * 4) = o;
    }
}

// ---------------- K1b: char CNN + maxpool -> fsp bf16 cols 300..419 --------
__global__ void k_char_cnn(const int* __restrict__ chars,
                           const float* __restrict__ char_emb,
                           const float* __restrict__ cw,
                           const float* __restrict__ cb,
                           ushort_t* __restrict__ Fh) {
    int n = blockIdx.x;                  // n = b*S + s
    int b = n >> 7;
    int s = n & 127;
    int np = b * 128 + s;
    __shared__ int cidx[W_];
    int t = threadIdx.x;
    if (t < W_) cidx[t] = chars[n * W_ + t];
    __syncthreads();
    if (t < CE_ * FN_) {
        int g = t >> 2;
        float w0 = cw[t*3+0], w1 = cw[t*3+1], w2 = cw[t*3+2];
        float x[W_];
        #pragma unroll
        for (int j = 0; j < W_; ++j) x[j] = char_emb[cidx[j] * CE_ + g];
        float m = -INFINITY;
        #pragma unroll
        for (int j = 0; j < W_ - 2; ++j) {
            float v = x[j]*w0 + x[j+1]*w1 + x[j+2]*w2;
            m = fmaxf(m, v);
        }
        Fh[(size_t)np * KL_ + WE_ + t] = f2b(m + cb[t]);
    }
    if (t < KL_ - FEAT_) Fh[(size_t)np * KL_ + FEAT_ + t] = 0;   // pad 420..447
}

// ---------------- conv weights -> bf16, k' = kr*512+ci ---------------------
__global__ void k_split_w(const float* __restrict__ conv_w,
                          ushort_t* __restrict__ Wt) {
    size_t i = (size_t)blockIdx.x * 256 + threadIdx.x;   // 3*1024*1536 total
    int ci = (int)(i & 511);
    int kr = (int)((i >> 9) % 3);
    size_t lo_ = i / 1536;                               // l*1024 + o
    Wt[i] = f2b(conv_w[lo_ * 1536 + (size_t)ci * 3 + kr]);
}

// ---------------- lin_w -> [c=512][k=448] bf16 (transposed, padded) --------
__global__ void k_split_lw(const float* __restrict__ lin_w,
                           ushort_t* __restrict__ Lh) {
    int k = blockIdx.x;                  // 0..447
    int c = threadIdx.x;                 // 0..511
    float v = (k < FEAT_) ? lin_w[(size_t)k * C_ + c] : 0.f;
    Lh[(size_t)c * KL_ + k] = f2b(v);
}

// ---------------- fc_w [512][20] -> fwT [20][512] fp32 ---------------------
__global__ void k_split_fw(const float* __restrict__ fc_w, float* __restrict__ fwT) {
    int idx = blockIdx.x * 256 + threadIdx.x;   // 10240
    if (idx < NT_ * C_) {
        int j = idx >> 9, c = idx & 511;
        fwT[idx] = fc_w[(size_t)c * NT_ + j];
    }
}

// ---------------- zero the pad rows (s'=0, s'=129) of h buffers ------------
__global__ void k_zero_pad(ushort_t* b0, ushort_t* b1) {
    ushort_t* buf = blockIdx.y ? b1 : b0;
    int b = blockIdx.x;
    int t = threadIdx.x;                 // 256 threads; row = 512 bf16 = 256 uints
    unsigned* r0 = (unsigned*)(buf + ((size_t)b * 130 + 0) * 512);
    unsigned* r1 = (unsigned*)(buf + ((size_t)b * 130 + 129) * 512);
    r0[t] = 0u; r1[t] = 0u;
}

// ---------------- K2: linear 420->512 as bf16 MFMA GEMM --------------------
__global__ __launch_bounds__(256) void k_lin_gemm(
    const ushort_t* __restrict__ Lh, const ushort_t* __restrict__ Fh,
    const float* __restrict__ lb, ushort_t* __restrict__ Oh)
{
    __shared__ short lds[8192];          // A, B tiles 4096 shorts each
    short* AhS = lds;
    short* BhS = lds + 4096;

    const int bid = blockIdx.x;
    const int c0 = (bid & 3) << 7;
    const int n0 = (bid >> 2) << 7;
    const int t = threadIdx.x;
    const int w = t >> 6;
    const int lane = t & 63;
    const int wr = w >> 1, wc = w & 1;

    const int srow0 = (w << 5) + (lane >> 2);
    const int srow1 = srow0 + 16;
    const int j0 = (lane & 3) ^ ((srow0 >> 1) & 3);
    const int j1 = (lane & 3) ^ ((srow1 >> 1) & 3);
    const size_t aoff0 = (size_t)(c0 + srow0) * KL_ + j0 * 8;
    const size_t aoff1 = (size_t)(c0 + srow1) * KL_ + j1 * 8;
    const size_t boff0 = (size_t)(n0 + srow0) * KL_ + j0 * 8;
    const size_t boff1 = (size_t)(n0 + srow1) * KL_ + j1 * 8;
    const int wofs = w << 10;

    const int lr = lane & 15, kg = lane >> 4;
    int aro[4], bro[4];
    #pragma unroll
    for (int m = 0; m < 4; ++m) { int r = (wr << 6) + (m << 4) + lr; aro[m] = (r << 5) + ((kg ^ ((r >> 1) & 3)) << 3); }
    #pragma unroll
    for (int n = 0; n < 4; ++n) { int r = (wc << 6) + (n << 4) + lr; bro[n] = (r << 5) + ((kg ^ ((r >> 1) & 3)) << 3); }

    f32x4 acc[4][4];
    #pragma unroll
    for (int m = 0; m < 4; ++m)
        #pragma unroll
        for (int n = 0; n < 4; ++n) acc[m][n] = (f32x4){0.f, 0.f, 0.f, 0.f};

    for (int k0 = 0; k0 < KL_; k0 += 32) {
        gload16(Lh + aoff0 + k0, AhS + wofs);
        gload16(Lh + aoff1 + k0, AhS + wofs + 512);
        gload16(Fh + boff0 + k0, BhS + wofs);
        gload16(Fh + boff1 + k0, BhS + wofs + 512);
        __syncthreads();
        bf16x8 avh[4], bvh[4];
        #pragma unroll
        for (int m = 0; m < 4; ++m) avh[m] = *(const bf16x8*)(AhS + aro[m]);
        #pragma unroll
        for (int n = 0; n < 4; ++n) bvh[n] = *(const bf16x8*)(BhS + bro[n]);
        #pragma unroll
        for (int m = 0; m < 4; ++m)
            #pragma unroll
            for (int n = 0; n < 4; ++n)
                acc[m][n] = __builtin_amdgcn_mfma_f32_16x16x32_bf16(avh[m], bvh[n], acc[m][n], 0, 0, 0);
        __syncthreads();
    }

    #pragma unroll
    for (int m = 0; m < 4; ++m) {
        const int c = c0 + (wr << 6) + (m << 4) + (kg << 2);
        float4 bb = *(const float4*)(lb + c);
        #pragma unroll
        for (int n = 0; n < 4; ++n) {
            const int np = n0 + (wc << 6) + (n << 4) + lr;
            const int b = np >> 7, s = np & 127;
            ushort4 h4;
            h4.x = f2b(acc[m][n][0] + bb.x);
            h4.y = f2b(acc[m][n][1] + bb.y);
            h4.z = f2b(acc[m][n][2] + bb.z);
            h4.w = f2b(acc[m][n][3] + bb.w);
            *(ushort4*)(Oh + ((size_t)b * 130 + s + 1) * 512 + c) = h4;
        }
    }
}

// ---------------- K3: GLU conv layer, BN=256 (2 batches/block), 8 waves ----
// Grid 256: co panel = bid&7 (XCD-pinned), batch pair = bid>>3.
// Per ci0 iter: stage A = 3 kr x [128][32] (3 gload/wave) + B = 2 slabs of
// 144 rows (2-3 gload/wave); 48 MFMA per wave.  Epilogue g-exchange via
// 4x[64][68] f32 LDS (aliases tiles).
__global__ __launch_bounds__(512) void k_conv_gemm(
    const ushort_t* __restrict__ Wt, const ushort_t* __restrict__ Ht,
    const float* __restrict__ cb,          // conv_b + l*1024
    ushort_t* __restrict__ Ot)
{
    __shared__ float g_lds[4 * 64 * 68];   // 69632 B; tiles alias first 43008 B
    short* AS = (short*)g_lds;             // 3 kr x 4096 shorts
    short* BS = AS + 12288;                // 2 slabs x 4608 shorts

    const int bid  = blockIdx.x;
    const int co0  = (bid & 7) << 6;       // 64 output channels; co == XCD id
    const int b0   = (bid >> 3) << 1;      // batch pair
    const int t    = threadIdx.x;
    const int w    = t >> 6;               // wave 0..7
    const int lane = t & 63;
    const int wr   = w >> 2;               // 0: a-rows, 1: g-rows
    const int wc   = w & 3;                // 64-col segment of 256 (2 batches)

    // A staging: wave w stages rows [w*16, w*16+16) of the 128-row tile
    const int srow = (w << 4) + (lane >> 2);
    const int jA = (lane & 3) ^ ((srow >> 1) & 3);
    const int coA = (srow < 64) ? (co0 + srow) : (512 + co0 + srow - 64);
    const size_t aoff = (size_t)coA * 1536 + jA * 8;
    const int lrow = lane >> 2;

    const int lr = lane & 15, kg = lane >> 4;
    int aro[4];
    #pragma unroll
    for (int m = 0; m < 4; ++m) { int r = (wr << 6) + (m << 4) + lr; aro[m] = (r << 5) + ((kg ^ ((r >> 1) & 3)) << 3); }
    int bro[3][4];
    const int slab = wc >> 1;
    const int s_off = (wc & 1) << 6;
    #pragma unroll
    for (int kr = 0; kr < 3; ++kr)
        #pragma unroll
        for (int n = 0; n < 4; ++n) {
            int r = s_off + (n << 4) + lr + kr;
            bro[kr][n] = slab * 4608 + (r << 5) + ((kg ^ ((r >> 1) & 3)) << 3);
        }

    f32x4 acc[4][4];
    #pragma unroll
    for (int m = 0; m < 4; ++m)
        #pragma unroll
        for (int n = 0; n < 4; ++n) acc[m][n] = (f32x4){0.f, 0.f, 0.f, 0.f};

    for (int ci0 = 0; ci0 < 512; ci0 += 32) {
        // A: one gload per kr per wave
        #pragma unroll
        for (int kr = 0; kr < 3; ++kr)
            gload16(Wt + aoff + kr * 512 + ci0, AS + kr * 4096 + (w << 9));
        // B: 18 groups (2 slabs x 9) across 8 waves
        for (int i = w; i < 18; i += 8) {
            const int sl2 = i / 9, grp = i - sl2 * 9;
            const int rr = (grp << 4) + lrow;
            const int sj = (lane & 3) ^ ((rr >> 1) & 3);
            gload16(Ht + ((size_t)(b0 + sl2) * 130 + rr) * 512 + ci0 + sj * 8,
                    BS + sl2 * 4608 + (grp << 9));
        }
        __syncthreads();
        #pragma unroll
        for (int kr = 0; kr < 3; ++kr) {
            const short* A_h = AS + kr * 4096;
            bf16x8 avh[4], bvh[4];
            #pragma unroll
            for (int m = 0; m < 4; ++m) avh[m] = *(const bf16x8*)(A_h + aro[m]);
            #pragma unroll
            for (int n = 0; n < 4; ++n) bvh[n] = *(const bf16x8*)(BS + bro[kr][n]);
            #pragma unroll
            for (int m = 0; m < 4; ++m)
                #pragma unroll
                for (int n = 0; n < 4; ++n)
                    acc[m][n] = __builtin_amdgcn_mfma_f32_16x16x32_bf16(avh[m], bvh[n], acc[m][n], 0, 0, 0);
        }
        __syncthreads();
    }

    // ---- fused GLU epilogue: g-waves (wr=1) hand acc to a-waves via LDS ----
    const float rs = 0.70710678118654752f;
    if (wr == 1) {
        #pragma unroll
        for (int m = 0; m < 4; ++m) {
            const int co_l = (m << 4) + (kg << 2);
            float4 bg = *(const float4*)(cb + 512 + co0 + co_l);
            #pragma unroll
            for (int n = 0; n < 4; ++n) {
                const int seg_s = (n << 4) + lr;
                float4 gv;
                gv.x = acc[m][n][0] + bg.x;
                gv.y = acc[m][n][1] + bg.y;
                gv.z = acc[m][n][2] + bg.z;
                gv.w = acc[m][n][3] + bg.w;
                *(float4*)&g_lds[((wc << 6) + seg_s) * 68 + co_l] = gv;
            }
        }
    }
    __syncthreads();
    if (wr == 0) {
        const int bb = b0 + (wc >> 1);
        #pragma unroll
        for (int m = 0; m < 4; ++m) {
            const int co_l = (m << 4) + (kg << 2);
            float4 ba = *(const float4*)(cb + co0 + co_l);
            #pragma unroll
            for (int n = 0; n < 4; ++n) {
                const int seg_s = (n << 4) + lr;
                float4 gv = *(const float4*)&g_lds[((wc << 6) + seg_s) * 68 + co_l];
                const int s_g = s_off + seg_s;
                size_t dst = ((size_t)bb * 130 + s_g + 1) * 512 + co0 + co_l;
                ushort4 rh = *(const ushort4*)(Ht + dst);
                float a0 = acc[m][n][0] + ba.x, g0 = gv.x;
                float a1 = acc[m][n][1] + ba.y, g1 = gv.y;
                float a2 = acc[m][n][2] + ba.z, g2 = gv.z;
                float a3 = acc[m][n][3] + ba.w, g3 = gv.w;
                ushort4 h4;
                h4.x = f2b((a0 / (1.f + expf(-g0)) + b2f(rh.x)) * rs);
                h4.y = f2b((a1 / (1.f + expf(-g1)) + b2f(rh.y)) * rs);
                h4.z = f2b((a2 / (1.f + expf(-g2)) + b2f(rh.z)) * rs);
                h4.w = f2b((a3 / (1.f + expf(-g3)) + b2f(rh.w)) * rs);
                *(ushort4*)(Ot + dst) = h4;
            }
        }
    }
}

// ---------------- K4: emissions, 512 blocks (b x s-chunk), LDS dot ---------
__global__ __launch_bounds__(256) void k_emis3(const ushort_t* __restrict__ hh,
                                               const float* __restrict__ fwT,  // [20][512]
                                               const float* __restrict__ fc_b,
                                               float* __restrict__ emis) {
    __shared__ short hlds[16 * 520];          // 16 rows, 512 ch (pad 520)
    __shared__ float wlds[20 * 516];          // 20 tags, 512 ch (pad 516)
    const int b  = blockIdx.y;
    const int sc = blockIdx.x;                // s chunk of 16
    const int t  = threadIdx.x;
    const int w  = t >> 6, lane = t & 63;

    #pragma unroll
    for (int i = 0; i < 4; ++i) {
        int r = w * 4 + i;
        gload16(hh + ((size_t)b * 130 + sc * 16 + r + 1) * 512 + lane * 8,
                hlds + r * 520);
    }
    for (int idx = t; idx < 20 * 128; idx += 256) {
        int j = idx >> 7, cq = (idx & 127) << 2;
        *(float4*)&wlds[j * 516 + cq] = *(const float4*)(fwT + j * 512 + cq);
    }
    __syncthreads();

    #pragma unroll
    for (int pass = 0; pass < 2; ++pass) {
        int slot = t + pass * 256;
        if (slot < 16 * NT_) {
            int r = slot / NT_, j = slot - r * NT_;
            const short* hp = hlds + r * 520;
            const float* wp = wlds + j * 516;
            float acc = 0.f;
            for (int c0 = 0; c0 < 512; c0 += 8) {
                u16x8 hv = *(const u16x8*)(hp + c0);
                float4 w0 = *(const float4*)(wp + c0);
                float4 w1 = *(const float4*)(wp + c0 + 4);
                acc += b2f(hv[0])*w0.x + b2f(hv[1])*w0.y + b2f(hv[2])*w0.z + b2f(hv[3])*w0.w
                     + b2f(hv[4])*w1.x + b2f(hv[5])*w1.y + b2f(hv[6])*w1.z + b2f(hv[7])*w1.w;
            }
            int s = sc * 16 + r;
            emis[((size_t)s * B_ + b) * NT_ + j] = acc + fc_b[j];
        }
    }
}

// ---------------- K5: bidirectional CRF, 4 waves ---------------------------
#define VMAX(a, b) __builtin_elementwise_max((a), (b))
#define MAX20T(mx, a0, a1, a2, a3, a4) \
    { f32x4 mv_ = VMAX(VMAX(VMAX(a0, a1), VMAX(a2, a3)), a4); \
      mx = fmaxf(fmaxf(mv_[0], mv_[1]), fmaxf(mv_[2], mv_[3])); }
#define SEL(ov, oi, av, ai, bv2, bi2) \
    { bool g_ = (bv2) > (av); ov = g_ ? (bv2) : (av); oi = g_ ? (bi2) : (ai); }
#define ARGMAX20(best, bi, v0, v1, v2, v3, v4) \
    { float p0v,p1v,p2v,p3v,p4v,p5v,p6v,p7v,p8v,p9v; \
      int   p0i,p1i,p2i,p3i,p4i,p5i,p6i,p7i,p8i,p9i; \
      SEL(p0v,p0i, v0[0],0,  v0[1],1);  SEL(p1v,p1i, v0[2],2,  v0[3],3); \
      SEL(p2v,p2i, v1[0],4,  v1[1],5);  SEL(p3v,p3i, v1[2],6,  v1[3],7); \
      SEL(p4v,p4i, v2[0],8,  v2[1],9);  SEL(p5v,p5i, v2[2],10, v2[3],11); \
      SEL(p6v,p6i, v3[0],12, v3[1],13); SEL(p7v,p7i, v3[2],14, v3[3],15); \
      SEL(p8v,p8i, v4[0],16, v4[1],17); SEL(p9v,p9i, v4[2],18, v4[3],19); \
      float q0v,q1v,q2v,q3v,q4v; int q0i,q1i,q2i,q3i,q4i; \
      SEL(q0v,q0i,p0v,p0i,p1v,p1i); SEL(q1v,q1i,p2v,p2i,p3v,p3i); \
      SEL(q2v,q2i,p4v,p4i,p5v,p5i); SEL(q3v,q3i,p6v,p6i,p7v,p7i); \
      SEL(q4v,q4i,p8v,p8i,p9v,p9i); \
      float r0v,r1v; int r0i,r1i; \
      SEL(r0v,r0i,q0v,q0i,q1v,q1i); SEL(r1v,r1i,q2v,q2i,q3v,q3i); \
      float s0v; int s0i; \
      SEL(s0v,s0i,r0v,r0i,r1v,r1i); \
      SEL(best,bi,s0v,s0i,q4v,q4i); }
#define EXPC(d, s) d[0]=__builtin_amdgcn_exp2f(s[0]*LOG2E_); d[1]=__builtin_amdgcn_exp2f(s[1]*LOG2E_); \
                   d[2]=__builtin_amdgcn_exp2f(s[2]*LOG2E_); d[3]=__builtin_amdgcn_exp2f(s[3]*LOG2E_)
#define LGKM0() asm volatile("s_waitcnt lgkmcnt(0)" ::: "memory")

__global__ __launch_bounds__(256) void k_crf(const float* __restrict__ emis,
                                             const int* __restrict__ words,
                                             const int* __restrict__ tags,
                                             const float* __restrict__ tstart,
                                             const float* __restrict__ tend,
                                             const float* __restrict__ ttrans,
                                             float* __restrict__ nll,
                                             float* __restrict__ out) {
    __shared__ float e_lds[S_ * NT_];          // 10240 B
    __shared__ float pe_lds[S_ * NT_];         // 10240 B  exp(emis)
    __shared__ int   P_lds[S_ * NT_];          // 10240 B  pointers (t=1..127)
    __shared__ float brA[32], brB[32], brC[32], brD[32];
    __shared__ float Fv[NT_], Gv[NT_], a63[NT_], g63[NT_];
    __shared__ float CfL, CbL;
    __shared__ int tag63L;
    const int b = blockIdx.x;
    const int t = threadIdx.x;
    const int w = t >> 6;
    const int ln = t & 63;

    for (int idx = t; idx < S_ * NT_; idx += 256) {
        int tt = idx / NT_, j = idx - tt * NT_;
        float ev = emis[((size_t)tt * B_ + b) * NT_ + j];
        e_lds[idx] = ev;
        pe_lds[idx] = __builtin_amdgcn_exp2f(ev * LOG2E_);
    }
    __syncthreads();

    unsigned long long mlo = __ballot(words[ln * B_ + b] != 0);
    unsigned long long mhi = __ballot(words[(64 + ln) * B_ + b] != 0);
    const bool act = ln < NT_;
    const int jc = act ? ln : 0;
    float part = 0.f;

    #define MBIT(tt) ((((tt) < 64 ? (mlo >> (tt)) : (mhi >> ((tt) - 64))) & 1ull) != 0)

    if (w == 0) {
        for (int tt = ln; tt < S_; tt += 64) {
            int tgc = tags[tt * B_ + b];
            bool m = MBIT(tt);
            if (tt == 0) {
                part += tstart[tgc] + e_lds[tgc];
            } else if (m) {
                int tgp = tags[(tt - 1) * B_ + b];
                part += ttrans[tgp * NT_ + tgc] + e_lds[tt * NT_ + tgc];
            }
        }
        #pragma unroll
        for (int o = 32; o >= 1; o >>= 1) part += __shfl_down(part, o);

        f32x4 t0, t1, t2, t3, t4;
        #define LDTC(v, q) v = (f32x4){ ttrans[(4*(q)+0)*NT_ + jc], ttrans[(4*(q)+1)*NT_ + jc], \
                                        ttrans[(4*(q)+2)*NT_ + jc], ttrans[(4*(q)+3)*NT_ + jc] }
        LDTC(t0, 0); LDTC(t1, 1); LDTC(t2, 2); LDTC(t3, 3); LDTC(t4, 4);
        f32x4 E0, E1, E2, E3, E4;
        EXPC(E0, t0); EXPC(E1, t1); EXPC(E2, t2); EXPC(E3, t3); EXPC(E4, t4);

        float a0own = tstart[jc] + e_lds[jc];
        if (act) brA[ln] = a0own;
        LGKM0();
        f32x4 a0 = *(const f32x4*)&brA[0];
        f32x4 a1 = *(const f32x4*)&brA[4];
        f32x4 a2 = *(const f32x4*)&brA[8];
        f32x4 a3 = *(const f32x4*)&brA[12];
        f32x4 a4 = *(const f32x4*)&brA[16];
        float m0; MAX20T(m0, a0, a1, a2, a3, a4);
        float beta = __builtin_amdgcn_exp2f((a0own - m0) * LOG2E_);
        int L2 = 0;
        for (int tt = 1; tt < 64; ++tt) {
            if (MBIT(tt)) {
                float pe = pe_lds[tt * NT_ + jc];
                if (act) brA[ln] = beta;
                LGKM0();
                f32x4 b0 = *(const f32x4*)&brA[0];
                f32x4 b1 = *(const f32x4*)&brA[4];
                f32x4 b2 = *(const f32x4*)&brA[8];
                f32x4 b3 = *(const f32x4*)&brA[12];
                f32x4 b4 = *(const f32x4*)&brA[16];
                float mx; MAX20T(mx, b0, b1, b2, b3, b4);
                f32x4 pr = b0 * E0 + b1 * E1 + b2 * E2 + b3 * E3 + b4 * E4;
                float dot = (pr[0] + pr[1]) + (pr[2] + pr[3]);
                unsigned bits; __builtin_memcpy(&bits, &mx, 4);
                int ex = (int)((bits >> 23) & 255u) - 127;
                unsigned rb = (unsigned)(127 - ex) << 23;
                float r; __builtin_memcpy(&r, &rb, 4);
                L2 += ex;
                beta = dot * r * pe;
            }
        }
        if (act) Fv[ln] = beta;
        if (ln == 0) CfL = m0 + (float)L2 * LN2_;
    } else if (w == 1) {
        f32x4 r0, r1, r2, r3, r4;
        #define LDTR(v, q) v = (f32x4){ ttrans[jc*NT_ + 4*(q)+0], ttrans[jc*NT_ + 4*(q)+1], \
                                        ttrans[jc*NT_ + 4*(q)+2], ttrans[jc*NT_ + 4*(q)+3] }
        LDTR(r0, 0); LDTR(r1, 1); LDTR(r2, 2); LDTR(r3, 3); LDTR(r4, 4);
        f32x4 E0, E1, E2, E3, E4;
        EXPC(E0, r0); EXPC(E1, r1); EXPC(E2, r2); EXPC(E3, r3); EXPC(E4, r4);
        f32x4 d0 = (f32x4){ tend[0],  tend[1],  tend[2],  tend[3]  };
        f32x4 d1 = (f32x4){ tend[4],  tend[5],  tend[6],  tend[7]  };
        f32x4 d2 = (f32x4){ tend[8],  tend[9],  tend[10], tend[11] };
        f32x4 d3 = (f32x4){ tend[12], tend[13], tend[14], tend[15] };
        f32x4 d4 = (f32x4){ tend[16], tend[17], tend[18], tend[19] };
        float mend; MAX20T(mend, d0, d1, d2, d3, d4);
        float G = __builtin_amdgcn_exp2f((tend[jc] - mend) * LOG2E_);
        int L2b = 0;
        for (int tt = 126; tt >= 63; --tt) {
            if (MBIT(tt + 1)) {
                float w_own = G * pe_lds[(tt + 1) * NT_ + jc];
                if (act) brB[ln] = w_own;
                LGKM0();
                f32x4 q0 = *(const f32x4*)&brB[0];
                f32x4 q1 = *(const f32x4*)&brB[4];
                f32x4 q2 = *(const f32x4*)&brB[8];
                f32x4 q3 = *(const f32x4*)&brB[12];
                f32x4 q4 = *(const f32x4*)&brB[16];
                float mx; MAX20T(mx, q0, q1, q2, q3, q4);
                f32x4 pr = q0 * E0 + q1 * E1 + q2 * E2 + q3 * E3 + q4 * E4;
                float dot = (pr[0] + pr[1]) + (pr[2] + pr[3]);
                unsigned bits; __builtin_memcpy(&bits, &mx, 4);
                int ex = (int)((bits >> 23) & 255u) - 127;
                unsigned rb = (unsigned)(127 - ex) << 23;
                float r; __builtin_memcpy(&r, &rb, 4);
                L2b += ex;
                G = dot * r;
            }
        }
        if (act) Gv[ln] = G;
        if (ln == 0) CbL = mend + (float)L2b * LN2_;
    } else if (w == 2) {
        f32x4 t0, t1, t2, t3, t4;
        LDTC(t0, 0); LDTC(t1, 1); LDTC(t2, 2); LDTC(t3, 3); LDTC(t4, 4);
        float sown = tstart[jc] + e_lds[jc];
        if (act) brC[ln] = sown;
        LGKM0();
        for (int tt = 1; tt < 64; ++tt) {
            float e = e_lds[tt * NT_ + jc];
            f32x4 a0 = *(const f32x4*)&brC[0];
            f32x4 a1 = *(const f32x4*)&brC[4];
            f32x4 a2 = *(const f32x4*)&brC[8];
            f32x4 a3 = *(const f32x4*)&brC[12];
            f32x4 a4 = *(const f32x4*)&brC[16];
            f32x4 v0 = a0 + t0, v1 = a1 + t1, v2 = a2 + t2, v3 = a3 + t3, v4 = a4 + t4;
            float best; int bi;
            ARGMAX20(best, bi, v0, v1, v2, v3, v4);
            bool m = MBIT(tt);
            float nxt = best + e;
            sown = m ? nxt : sown;
            if (act) {
                brC[ln] = sown;
                P_lds[tt * NT_ + ln] = m ? bi : ln;
            }
            LGKM0();
        }
        if (act) a63[ln] = sown;
    } else {
        f32x4 r0, r1, r2, r3, r4;
        LDTR(r0, 0); LDTR(r1, 1); LDTR(r2, 2); LDTR(r3, 3); LDTR(r4, 4);
        float gown = tend[jc];
        if (act) brD[ln] = gown + e_lds[127 * NT_ + jc];
        LGKM0();
        for (int tt = 126; tt >= 63; --tt) {
            f32x4 q0 = *(const f32x4*)&brD[0];
            f32x4 q1 = *(const f32x4*)&brD[4];
            f32x4 q2 = *(const f32x4*)&brD[8];
            f32x4 q3 = *(const f32x4*)&brD[12];
            f32x4 q4 = *(const f32x4*)&brD[16];
            f32x4 v0 = r0 + q0, v1 = r1 + q1, v2 = r2 + q2, v3 = r3 + q3, v4 = r4 + q4;
            float best; int bi;
            ARGMAX20(best, bi, v0, v1, v2, v3, v4);
            bool m = MBIT(tt + 1);
            gown = m ? best : gown;
            if (act) {
                P_lds[(tt + 1) * NT_ + ln] = m ? bi : ln;
                brD[ln] = gown + e_lds[tt * NT_ + jc];
            }
            LGKM0();
        }
        if (act) g63[ln] = gown;
    }
    __syncthreads();

    if (t == 0) {
        float zf = 0.f;
        #pragma unroll
        for (int j = 0; j < NT_; ++j) zf += Fv[j] * Gv[j];
        float logz = CfL + CbL + __builtin_amdgcn_logf(zf) * LN2_;
        int cnt = __popcll(mlo) + __popcll(mhi);
        float num = part + tend[tags[(cnt - 1) * B_ + b]];
        nll[b] = logz - num;
        float bv = a63[0] + g63[0]; int bt = 0;
        #pragma unroll
        for (int j = 1; j < NT_; ++j) {
            float v = a63[j] + g63[j];
            if (v > bv) { bv = v; bt = j; }
        }
        tag63L = bt;
    }
    __syncthreads();

    if (t == 128) {
        int tag = tag63L;
        out[63 * B_ + b] = (float)tag;
        for (int tt = 63; tt >= 1; --tt) {
            tag = P_lds[tt * NT_ + tag];
            out[(tt - 1) * B_ + b] = (float)tag;
        }
    }
    if (t == 192) {
        int tag = tag63L;
        for (int tt = 64; tt < 128; ++tt) {
            tag = P_lds[tt * NT_ + tag];
            out[tt * B_ + b] = (float)tag;
        }
    }
}

// ---------------- K7: final loss reduce ------------------------------------
__global__ void k_loss(const float* __restrict__ nll, float* __restrict__ out) {
    float v = nll[threadIdx.x];
    #pragma unroll
    for (int o = 32; o >= 1; o >>= 1) v += __shfl_down(v, o);
    if (threadIdx.x == 0) out[S_ * B_] = v;
}

extern "C" void kernel_launch(void* const* d_in, const int* in_sizes, int n_in,
                              void* d_out, int out_size, void* d_ws, size_t ws_size,
                              hipStream_t stream) {
    (void)in_sizes; (void)n_in; (void)out_size; (void)ws_size;
    const int*   words     = (const int*)d_in[0];
    const int*   chars     = (const int*)d_in[1];
    const int*   tags      = (const int*)d_in[2];
    const float* word_emb  = (const float*)d_in[3];
    const float* char_emb  = (const float*)d_in[4];
    const float* ccw       = (const float*)d_in[5];
    const float* ccb       = (const float*)d_in[6];
    const float* lin_w     = (const float*)d_in[7];
    const float* lin_b     = (const float*)d_in[8];
    const float* conv_w    = (const float*)d_in[9];
    const float* conv_b    = (const float*)d_in[10];
    const float* fc_w      = (const float*)d_in[11];
    const float* fc_b      = (const float*)d_in[12];
    const float* crf_start = (const float*)d_in[13];
    const float* crf_end   = (const float*)d_in[14];
    const float* crf_trans = (const float*)d_in[15];

    float* ws   = (float*)d_ws;
    float* em   = ws + EM_OFF;
    float* nll  = ws + NLL_OFF;
    ushort_t* h0  = (ushort_t*)(ws + H0_OFF);
    ushort_t* h1  = (ushort_t*)(ws + H1_OFF);
    ushort_t* wsp = (ushort_t*)(ws + WS_OFF);
    ushort_t* lwp = (ushort_t*)(ws + LW_OFF);
    ushort_t* fsp = (ushort_t*)(ws + FS_OFF);
    float* fwT  = ws + FW_OFF;
    float* out  = (float*)d_out;

    k_word_gather<<<S_ * B_, 128, 0, stream>>>(words, word_emb, fsp);
    k_char_cnn<<<B_ * S_, 128, 0, stream>>>(chars, char_emb, ccw, ccb, fsp);
    k_split_w<<<18432, 256, 0, stream>>>(conv_w, wsp);
    k_split_lw<<<KL_, 512, 0, stream>>>(lin_w, lwp);
    k_split_fw<<<40, 256, 0, stream>>>(fc_w, fwT);
    k_lin_gemm<<<256, 256, 0, stream>>>(lwp, fsp, lin_b, h0);
    k_zero_pad<<<dim3(64, 2), 256, 0, stream>>>(h0, h1);

    k_conv_gemm<<<256, 512, 0, stream>>>(wsp,              h0, conv_b,        h1);
    k_conv_gemm<<<256, 512, 0, stream>>>(wsp + WLAYER,     h1, conv_b + 1024, h0);
    k_conv_gemm<<<256, 512, 0, stream>>>(wsp + 2*WLAYER,   h0, conv_b + 2048, h1);

    k_emis3<<<dim3(8, B_), 256, 0, stream>>>(h1, fwT, fc_b, em);
    k_crf<<<B_, 256, 0, stream>>>(em, words, tags, crf_start, crf_end, crf_trans, nll, out);
    k_loss<<<1, 64, 0, stream>>>(nll, out);
}

// Round 14
// 185.153 us; speedup vs baseline: 1.0495x; 1.0495x over previous
//
#include <hip/hip_runtime.h>
#include <math.h>

typedef unsigned short ushort_t;
typedef short bf16x8 __attribute__((ext_vector_type(8)));
typedef float f32x4 __attribute__((ext_vector_type(4)));
typedef unsigned short u16x8 __attribute__((ext_vector_type(8)));

#define S_ 128
#define B_ 64
#define W_ 16
#define CE_ 30
#define FN_ 4
#define WE_ 300
#define FEAT_ 420
#define C_ 512
#define NT_ 20
#define KL_ 448          // padded K for the 420->512 linear

#define LOG2E_ 1.44269504088896340736f
#define LN2_   0.69314718055994530942f

// ---- workspace layout (float units) ----
#define EM_OFF   0                       // 163,840 floats
#define NLL_OFF  163840                  // 64
#define H0_OFF   163968                  // each h buffer: 64*130*512 bf16 = 2,129,920 floats
#define HBUF_F   2129920
#define H1_OFF   (H0_OFF + HBUF_F)
#define WS_OFF   (H1_OFF + HBUF_F)       // conv w bf16: 3*1024*1536 = 2,359,296 floats
#define WSP_F    2359296
#define LW_OFF   (WS_OFF + WSP_F)        // lin_w bf16: 512*448 = 114,688 floats
#define FS_OFF   (LW_OFF + 114688)       // wf bf16: 8192*448 = 1,835,008 floats
#define FW_OFF   (FS_OFF + 1835008)      // fc_w transposed [20][512] fp32 = 10,240 floats
#define WLAYER   (1024*1536)             // ushort elems per layer

__device__ __forceinline__ float b2f(ushort_t h) {
    unsigned u = ((unsigned)h) << 16;
    float f; __builtin_memcpy(&f, &u, 4); return f;
}
__device__ __forceinline__ ushort_t f2b(float f) {   // round-to-nearest-even
    unsigned u; __builtin_memcpy(&u, &f, 4);
    unsigned r = (u + 0x7FFFu + ((u >> 16) & 1u)) >> 16;
    return (ushort_t)r;
}
__device__ __forceinline__ void gload16(const void* g, void* l) {
    __builtin_amdgcn_global_load_lds((const __attribute__((address_space(1))) void*)g,
                                     (__attribute__((address_space(3))) void*)l,
                                     16, 0, 0);
}

// ---------------- K1a: word embedding gather -> fsp bf16 cols 0..299 -------
__global__ void k_word_gather(const int* __restrict__ words,
                              const float* __restrict__ word_emb,
                              ushort_t* __restrict__ Fh) {
    int n = blockIdx.x;                  // n = s*B + b
    int s = n >> 6, b = n & 63;
    int np = b * 128 + s;
    int wid = words[n];
    int t = threadIdx.x;
    if (t < WE_ / 4) {
        float4 v = ((const float4*)(word_emb + (size_t)wid * WE_))[t];
        ushort4 o;
        o.x = f2b(v.x); o.y = f2b(v.y); o.z = f2b(v.z); o.w = f2b(v.w);
        *(ushort4*)(Fh + (size_t)np * KL_ + t * 4) = o;
    }
}

// ---------------- K1b: char CNN + maxpool -> fsp bf16 cols 300..419 --------
__global__ void k_char_cnn(const int* __restrict__ chars,
                           const float* __restrict__ char_emb,
                           const float* __restrict__ cw,
                           const float* __restrict__ cb,
                           ushort_t* __restrict__ Fh) {
    int n = blockIdx.x;                  // n = b*S + s
    int b = n >> 7;
    int s = n & 127;
    int np = b * 128 + s;
    __shared__ int cidx[W_];
    int t = threadIdx.x;
    if (t < W_) cidx[t] = chars[n * W_ + t];
    __syncthreads();
    if (t < CE_ * FN_) {
        int g = t >> 2;
        float w0 = cw[t*3+0], w1 = cw[t*3+1], w2 = cw[t*3+2];
        float x[W_];
        #pragma unroll
        for (int j = 0; j < W_; ++j) x[j] = char_emb[cidx[j] * CE_ + g];
        float m = -INFINITY;
        #pragma unroll
        for (int j = 0; j < W_ - 2; ++j) {
            float v = x[j]*w0 + x[j+1]*w1 + x[j+2]*w2;
            m = fmaxf(m, v);
        }
        Fh[(size_t)np * KL_ + WE_ + t] = f2b(m + cb[t]);
    }
    if (t < KL_ - FEAT_) Fh[(size_t)np * KL_ + FEAT_ + t] = 0;   // pad 420..447
}

// ---------------- conv weights -> bf16, k' = kr*512+ci ---------------------
__global__ void k_split_w(const float* __restrict__ conv_w,
                          ushort_t* __restrict__ Wt) {
    size_t i = (size_t)blockIdx.x * 256 + threadIdx.x;   // 3*1024*1536 total
    int ci = (int)(i & 511);
    int kr = (int)((i >> 9) % 3);
    size_t lo_ = i / 1536;                               // l*1024 + o
    Wt[i] = f2b(conv_w[lo_ * 1536 + (size_t)ci * 3 + kr]);
}

// ---------------- lin_w -> [c=512][k=448] bf16 (transposed, padded) --------
__global__ void k_split_lw(const float* __restrict__ lin_w,
                           ushort_t* __restrict__ Lh) {
    int k = blockIdx.x;                  // 0..447
    int c = threadIdx.x;                 // 0..511
    float v = (k < FEAT_) ? lin_w[(size_t)k * C_ + c] : 0.f;
    Lh[(size_t)c * KL_ + k] = f2b(v);
}

// ---------------- fc_w [512][20] -> fwT [20][512] fp32 ---------------------
__global__ void k_split_fw(const float* __restrict__ fc_w, float* __restrict__ fwT) {
    int idx = blockIdx.x * 256 + threadIdx.x;   // 10240
    if (idx < NT_ * C_) {
        int j = idx >> 9, c = idx & 511;
        fwT[idx] = fc_w[(size_t)c * NT_ + j];
    }
}

// ---------------- zero the pad rows (s'=0, s'=129) of h buffers ------------
__global__ void k_zero_pad(ushort_t* b0, ushort_t* b1) {
    ushort_t* buf = blockIdx.y ? b1 : b0;
    int b = blockIdx.x;
    int t = threadIdx.x;                 // 256 threads; row = 512 bf16 = 256 uints
    unsigned* r0 = (unsigned*)(buf + ((size_t)b * 130 + 0) * 512);
    unsigned* r1 = (unsigned*)(buf + ((size_t)b * 130 + 129) * 512);
    r0[t] = 0u; r1[t] = 0u;
}

// ---------------- K2: linear 420->512 as bf16 MFMA GEMM --------------------
__global__ __launch_bounds__(256) void k_lin_gemm(
    const ushort_t* __restrict__ Lh, const ushort_t* __restrict__ Fh,
    const float* __restrict__ lb, ushort_t* __restrict__ Oh)
{
    __shared__ short lds[8192];          // A, B tiles 4096 shorts each
    short* AhS = lds;
    short* BhS = lds + 4096;

    const int bid = blockIdx.x;
    const int c0 = (bid & 3) << 7;
    const int n0 = (bid >> 2) << 7;
    const int t = threadIdx.x;
    const int w = t >> 6;
    const int lane = t & 63;
    const int wr = w >> 1, wc = w & 1;

    const int srow0 = (w << 5) + (lane >> 2);
    const int srow1 = srow0 + 16;
    const int j0 = (lane & 3) ^ ((srow0 >> 1) & 3);
    const int j1 = (lane & 3) ^ ((srow1 >> 1) & 3);
    const size_t aoff0 = (size_t)(c0 + srow0) * KL_ + j0 * 8;
    const size_t aoff1 = (size_t)(c0 + srow1) * KL_ + j1 * 8;
    const size_t boff0 = (size_t)(n0 + srow0) * KL_ + j0 * 8;
    const size_t boff1 = (size_t)(n0 + srow1) * KL_ + j1 * 8;
    const int wofs = w << 10;

    const int lr = lane & 15, kg = lane >> 4;
    int aro[4], bro[4];
    #pragma unroll
    for (int m = 0; m < 4; ++m) { int r = (wr << 6) + (m << 4) + lr; aro[m] = (r << 5) + ((kg ^ ((r >> 1) & 3)) << 3); }
    #pragma unroll
    for (int n = 0; n < 4; ++n) { int r = (wc << 6) + (n << 4) + lr; bro[n] = (r << 5) + ((kg ^ ((r >> 1) & 3)) << 3); }

    f32x4 acc[4][4];
    #pragma unroll
    for (int m = 0; m < 4; ++m)
        #pragma unroll
        for (int n = 0; n < 4; ++n) acc[m][n] = (f32x4){0.f, 0.f, 0.f, 0.f};

    for (int k0 = 0; k0 < KL_; k0 += 32) {
        gload16(Lh + aoff0 + k0, AhS + wofs);
        gload16(Lh + aoff1 + k0, AhS + wofs + 512);
        gload16(Fh + boff0 + k0, BhS + wofs);
        gload16(Fh + boff1 + k0, BhS + wofs + 512);
        __syncthreads();
        bf16x8 avh[4], bvh[4];
        #pragma unroll
        for (int m = 0; m < 4; ++m) avh[m] = *(const bf16x8*)(AhS + aro[m]);
        #pragma unroll
        for (int n = 0; n < 4; ++n) bvh[n] = *(const bf16x8*)(BhS + bro[n]);
        #pragma unroll
        for (int m = 0; m < 4; ++m)
            #pragma unroll
            for (int n = 0; n < 4; ++n)
                acc[m][n] = __builtin_amdgcn_mfma_f32_16x16x32_bf16(avh[m], bvh[n], acc[m][n], 0, 0, 0);
        __syncthreads();
    }

    #pragma unroll
    for (int m = 0; m < 4; ++m) {
        const int c = c0 + (wr << 6) + (m << 4) + (kg << 2);
        float4 bb = *(const float4*)(lb + c);
        #pragma unroll
        for (int n = 0; n < 4; ++n) {
            const int np = n0 + (wc << 6) + (n << 4) + lr;
            const int b = np >> 7, s = np & 127;
            ushort4 h4;
            h4.x = f2b(acc[m][n][0] + bb.x);
            h4.y = f2b(acc[m][n][1] + bb.y);
            h4.z = f2b(acc[m][n][2] + bb.z);
            h4.w = f2b(acc[m][n][3] + bb.w);
            *(ushort4*)(Oh + ((size_t)b * 130 + s + 1) * 512 + c) = h4;
        }
    }
}

// ---------------- K3: GLU conv layer, 2-phase double-buffered MFMA GEMM ----
// R12 shape (BN=128, 4 waves, grid 512, co panel XCD-pinned) + double-buffer:
// prefetch of K-tile t+1 issued BEFORE compute of tile t; ONE barrier/iter.
// The compiler's vmcnt(0) drain before s_barrier then lands AFTER the MFMA
// phase, hiding L2 latency under compute.
#define CBUFS 16896                      // shorts per buffer: A 3*4096 + B 4608
__global__ __launch_bounds__(256) void k_conv_gemm(
    const ushort_t* __restrict__ Wt, const ushort_t* __restrict__ Ht,
    const float* __restrict__ cb,          // conv_b + l*1024
    ushort_t* __restrict__ Ot)
{
    __shared__ short lds2[2 * CBUFS];      // 67584 B; epilogue g_lds aliases base
    float* g_lds = (float*)lds2;           // 128*68 f32 = 34816 B

    const int bid  = blockIdx.x;
    const int co0  = (bid & 7) << 6;       // 64 output channels; co == XCD id
    const int b    = bid >> 3;
    const int t    = threadIdx.x;
    const int w    = t >> 6;               // wave 0..3
    const int lane = t & 63;
    const int wr   = w >> 1;               // 0: a-rows, 1: g-rows
    const int wc   = w & 1;                // s half

    const int srow0 = (w << 5) + (lane >> 2);
    const int srow1 = srow0 + 16;
    const int j0 = (lane & 3) ^ ((srow0 >> 1) & 3);
    const int j1 = (lane & 3) ^ ((srow1 >> 1) & 3);
    const int coA0 = (srow0 < 64) ? (co0 + srow0) : (512 + co0 + srow0 - 64);
    const int coA1 = (srow1 < 64) ? (co0 + srow1) : (512 + co0 + srow1 - 64);
    const size_t aoff0 = (size_t)coA0 * 1536 + j0 * 8;
    const size_t aoff1 = (size_t)coA1 * 1536 + j1 * 8;
    const int lrow = lane >> 2;
    const int wofs = w << 10;

    const int lr = lane & 15, kg = lane >> 4;
    int aro[4];
    #pragma unroll
    for (int m = 0; m < 4; ++m) { int r = (wr << 6) + (m << 4) + lr; aro[m] = (r << 5) + ((kg ^ ((r >> 1) & 3)) << 3); }
    int bro[3][4];
    #pragma unroll
    for (int kr = 0; kr < 3; ++kr)
        #pragma unroll
        for (int n = 0; n < 4; ++n) {
            int r = (wc << 6) + (n << 4) + lr + kr;
            bro[kr][n] = (r << 5) + ((kg ^ ((r >> 1) & 3)) << 3);
        }

    f32x4 acc[4][4];
    #pragma unroll
    for (int m = 0; m < 4; ++m)
        #pragma unroll
        for (int n = 0; n < 4; ++n) acc[m][n] = (f32x4){0.f, 0.f, 0.f, 0.f};

    // ---- prologue: stage tile 0 into buffer 0 ----
    {
        short* AS = lds2;
        short* BS = lds2 + 12288;
        #pragma unroll
        for (int kr = 0; kr < 3; ++kr) {
            gload16(Wt + aoff0 + kr * 512, AS + kr * 4096 + wofs);
            gload16(Wt + aoff1 + kr * 512, AS + kr * 4096 + wofs + 512);
        }
        for (int i = w; i < 9; i += 4) {
            const int rr = (i << 4) + lrow;
            const int sj = (lane & 3) ^ ((rr >> 1) & 3);
            gload16(Ht + ((size_t)b * 130 + rr) * 512 + sj * 8, BS + (i << 9));
        }
    }
    __syncthreads();

    for (int it = 0; it < 16; ++it) {
        const int cur = it & 1;
        // ---- prefetch tile it+1 into the other buffer ----
        if (it + 1 < 16) {
            const int ci0 = (it + 1) << 5;
            short* ASn = lds2 + (cur ^ 1) * CBUFS;
            short* BSn = ASn + 12288;
            #pragma unroll
            for (int kr = 0; kr < 3; ++kr) {
                gload16(Wt + aoff0 + kr * 512 + ci0, ASn + kr * 4096 + wofs);
                gload16(Wt + aoff1 + kr * 512 + ci0, ASn + kr * 4096 + wofs + 512);
            }
            for (int i = w; i < 9; i += 4) {
                const int rr = (i << 4) + lrow;
                const int sj = (lane & 3) ^ ((rr >> 1) & 3);
                gload16(Ht + ((size_t)b * 130 + rr) * 512 + ci0 + sj * 8, BSn + (i << 9));
            }
        }
        // ---- compute from current buffer ----
        const short* AS = lds2 + cur * CBUFS;
        const short* BS = AS + 12288;
        #pragma unroll
        for (int kr = 0; kr < 3; ++kr) {
            const short* A_h = AS + kr * 4096;
            bf16x8 avh[4], bvh[4];
            #pragma unroll
            for (int m = 0; m < 4; ++m) avh[m] = *(const bf16x8*)(A_h + aro[m]);
            #pragma unroll
            for (int n = 0; n < 4; ++n) bvh[n] = *(const bf16x8*)(BS + bro[kr][n]);
            #pragma unroll
            for (int m = 0; m < 4; ++m)
                #pragma unroll
                for (int n = 0; n < 4; ++n)
                    acc[m][n] = __builtin_amdgcn_mfma_f32_16x16x32_bf16(avh[m], bvh[n], acc[m][n], 0, 0, 0);
        }
        __syncthreads();   // drains vmcnt(0) AFTER compute -> prefetch latency hidden
    }

    // ---- fused GLU epilogue: g-waves hand their acc to a-waves via LDS ----
    const float rs = 0.70710678118654752f;
    if (wr == 1) {
        #pragma unroll
        for (int m = 0; m < 4; ++m) {
            const int co_l = (m << 4) + (kg << 2);
            float4 bg = *(const float4*)(cb + 512 + co0 + co_l);
            #pragma unroll
            for (int n = 0; n < 4; ++n) {
                const int s_l = (wc << 6) + (n << 4) + lr;
                float4 gv;
                gv.x = acc[m][n][0] + bg.x;
                gv.y = acc[m][n][1] + bg.y;
                gv.z = acc[m][n][2] + bg.z;
                gv.w = acc[m][n][3] + bg.w;
                *(float4*)&g_lds[s_l * 68 + co_l] = gv;
            }
        }
    }
    __syncthreads();
    if (wr == 0) {
        #pragma unroll
        for (int m = 0; m < 4; ++m) {
            const int co_l = (m << 4) + (kg << 2);
            float4 ba = *(const float4*)(cb + co0 + co_l);
            #pragma unroll
            for (int n = 0; n < 4; ++n) {
                const int s_l = (wc << 6) + (n << 4) + lr;
                float4 gv = *(const float4*)&g_lds[s_l * 68 + co_l];
                size_t dst = ((size_t)b * 130 + s_l + 1) * 512 + co0 + co_l;
                ushort4 rh = *(const ushort4*)(Ht + dst);
                float a0 = acc[m][n][0] + ba.x, g0 = gv.x;
                float a1 = acc[m][n][1] + ba.y, g1 = gv.y;
                float a2 = acc[m][n][2] + ba.z, g2 = gv.z;
                float a3 = acc[m][n][3] + ba.w, g3 = gv.w;
                ushort4 h4;
                h4.x = f2b((a0 / (1.f + expf(-g0)) + b2f(rh.x)) * rs);
                h4.y = f2b((a1 / (1.f + expf(-g1)) + b2f(rh.y)) * rs);
                h4.z = f2b((a2 / (1.f + expf(-g2)) + b2f(rh.z)) * rs);
                h4.w = f2b((a3 / (1.f + expf(-g3)) + b2f(rh.w)) * rs);
                *(ushort4*)(Ot + dst) = h4;
            }
        }
    }
}

// ---------------- K4: emissions, 512 blocks (b x s-chunk), LDS dot ---------
__global__ __launch_bounds__(256) void k_emis3(const ushort_t* __restrict__ hh,
                                               const float* __restrict__ fwT,  // [20][512]
                                               const float* __restrict__ fc_b,
                                               float* __restrict__ emis) {
    __shared__ short hlds[16 * 520];          // 16 rows, 512 ch (pad 520)
    __shared__ float wlds[20 * 516];          // 20 tags, 512 ch (pad 516)
    const int b  = blockIdx.y;
    const int sc = blockIdx.x;                // s chunk of 16
    const int t  = threadIdx.x;
    const int w  = t >> 6, lane = t & 63;

    #pragma unroll
    for (int i = 0; i < 4; ++i) {
        int r = w * 4 + i;
        gload16(hh + ((size_t)b * 130 + sc * 16 + r + 1) * 512 + lane * 8,
                hlds + r * 520);
    }
    for (int idx = t; idx < 20 * 128; idx += 256) {
        int j = idx >> 7, cq = (idx & 127) << 2;
        *(float4*)&wlds[j * 516 + cq] = *(const float4*)(fwT + j * 512 + cq);
    }
    __syncthreads();

    #pragma unroll
    for (int pass = 0; pass < 2; ++pass) {
        int slot = t + pass * 256;
        if (slot < 16 * NT_) {
            int r = slot / NT_, j = slot - r * NT_;
            const short* hp = hlds + r * 520;
            const float* wp = wlds + j * 516;
            float acc = 0.f;
            for (int c0 = 0; c0 < 512; c0 += 8) {
                u16x8 hv = *(const u16x8*)(hp + c0);
                float4 w0 = *(const float4*)(wp + c0);
                float4 w1 = *(const float4*)(wp + c0 + 4);
                acc += b2f(hv[0])*w0.x + b2f(hv[1])*w0.y + b2f(hv[2])*w0.z + b2f(hv[3])*w0.w
                     + b2f(hv[4])*w1.x + b2f(hv[5])*w1.y + b2f(hv[6])*w1.z + b2f(hv[7])*w1.w;
            }
            int s = sc * 16 + r;
            emis[((size_t)s * B_ + b) * NT_ + j] = acc + fc_b[j];
        }
    }
}

// ---------------- K5: bidirectional CRF, 4 waves ---------------------------
#define VMAX(a, b) __builtin_elementwise_max((a), (b))
#define MAX20T(mx, a0, a1, a2, a3, a4) \
    { f32x4 mv_ = VMAX(VMAX(VMAX(a0, a1), VMAX(a2, a3)), a4); \
      mx = fmaxf(fmaxf(mv_[0], mv_[1]), fmaxf(mv_[2], mv_[3])); }
#define SEL(ov, oi, av, ai, bv2, bi2) \
    { bool g_ = (bv2) > (av); ov = g_ ? (bv2) : (av); oi = g_ ? (bi2) : (ai); }
#define ARGMAX20(best, bi, v0, v1, v2, v3, v4) \
    { float p0v,p1v,p2v,p3v,p4v,p5v,p6v,p7v,p8v,p9v; \
      int   p0i,p1i,p2i,p3i,p4i,p5i,p6i,p7i,p8i,p9i; \
      SEL(p0v,p0i, v0[0],0,  v0[1],1);  SEL(p1v,p1i, v0[2],2,  v0[3],3); \
      SEL(p2v,p2i, v1[0],4,  v1[1],5);  SEL(p3v,p3i, v1[2],6,  v1[3],7); \
      SEL(p4v,p4i, v2[0],8,  v2[1],9);  SEL(p5v,p5i, v2[2],10, v2[3],11); \
      SEL(p6v,p6i, v3[0],12, v3[1],13); SEL(p7v,p7i, v3[2],14, v3[3],15); \
      SEL(p8v,p8i, v4[0],16, v4[1],17); SEL(p9v,p9i, v4[2],18, v4[3],19); \
      float q0v,q1v,q2v,q3v,q4v; int q0i,q1i,q2i,q3i,q4i; \
      SEL(q0v,q0i,p0v,p0i,p1v,p1i); SEL(q1v,q1i,p2v,p2i,p3v,p3i); \
      SEL(q2v,q2i,p4v,p4i,p5v,p5i); SEL(q3v,q3i,p6v,p6i,p7v,p7i); \
      SEL(q4v,q4i,p8v,p8i,p9v,p9i); \
      float r0v,r1v; int r0i,r1i; \
      SEL(r0v,r0i,q0v,q0i,q1v,q1i); SEL(r1v,r1i,q2v,q2i,q3v,q3i); \
      float s0v; int s0i; \
      SEL(s0v,s0i,r0v,r0i,r1v,r1i); \
      SEL(best,bi,s0v,s0i,q4v,q4i); }
#define EXPC(d, s) d[0]=__builtin_amdgcn_exp2f(s[0]*LOG2E_); d[1]=__builtin_amdgcn_exp2f(s[1]*LOG2E_); \
                   d[2]=__builtin_amdgcn_exp2f(s[2]*LOG2E_); d[3]=__builtin_amdgcn_exp2f(s[3]*LOG2E_)
#define LGKM0() asm volatile("s_waitcnt lgkmcnt(0)" ::: "memory")

__global__ __launch_bounds__(256) void k_crf(const float* __restrict__ emis,
                                             const int* __restrict__ words,
                                             const int* __restrict__ tags,
                                             const float* __restrict__ tstart,
                                             const float* __restrict__ tend,
                                             const float* __restrict__ ttrans,
                                             float* __restrict__ nll,
                                             float* __restrict__ out) {
    __shared__ float e_lds[S_ * NT_];          // 10240 B
    __shared__ float pe_lds[S_ * NT_];         // 10240 B  exp(emis)
    __shared__ int   P_lds[S_ * NT_];          // 10240 B  pointers (t=1..127)
    __shared__ float brA[32], brB[32], brC[32], brD[32];
    __shared__ float Fv[NT_], Gv[NT_], a63[NT_], g63[NT_];
    __shared__ float CfL, CbL;
    __shared__ int tag63L;
    const int b = blockIdx.x;
    const int t = threadIdx.x;
    const int w = t >> 6;
    const int ln = t & 63;

    for (int idx = t; idx < S_ * NT_; idx += 256) {
        int tt = idx / NT_, j = idx - tt * NT_;
        float ev = emis[((size_t)tt * B_ + b) * NT_ + j];
        e_lds[idx] = ev;
        pe_lds[idx] = __builtin_amdgcn_exp2f(ev * LOG2E_);
    }
    __syncthreads();

    unsigned long long mlo = __ballot(words[ln * B_ + b] != 0);
    unsigned long long mhi = __ballot(words[(64 + ln) * B_ + b] != 0);
    const bool act = ln < NT_;
    const int jc = act ? ln : 0;
    float part = 0.f;

    #define MBIT(tt) ((((tt) < 64 ? (mlo >> (tt)) : (mhi >> ((tt) - 64))) & 1ull) != 0)

    if (w == 0) {
        for (int tt = ln; tt < S_; tt += 64) {
            int tgc = tags[tt * B_ + b];
            bool m = MBIT(tt);
            if (tt == 0) {
                part += tstart[tgc] + e_lds[tgc];
            } else if (m) {
                int tgp = tags[(tt - 1) * B_ + b];
                part += ttrans[tgp * NT_ + tgc] + e_lds[tt * NT_ + tgc];
            }
        }
        #pragma unroll
        for (int o = 32; o >= 1; o >>= 1) part += __shfl_down(part, o);

        f32x4 t0, t1, t2, t3, t4;
        #define LDTC(v, q) v = (f32x4){ ttrans[(4*(q)+0)*NT_ + jc], ttrans[(4*(q)+1)*NT_ + jc], \
                                        ttrans[(4*(q)+2)*NT_ + jc], ttrans[(4*(q)+3)*NT_ + jc] }
        LDTC(t0, 0); LDTC(t1, 1); LDTC(t2, 2); LDTC(t3, 3); LDTC(t4, 4);
        f32x4 E0, E1, E2, E3, E4;
        EXPC(E0, t0); EXPC(E1, t1); EXPC(E2, t2); EXPC(E3, t3); EXPC(E4, t4);

        float a0own = tstart[jc] + e_lds[jc];
        if (act) brA[ln] = a0own;
        LGKM0();
        f32x4 a0 = *(const f32x4*)&brA[0];
        f32x4 a1 = *(const f32x4*)&brA[4];
        f32x4 a2 = *(const f32x4*)&brA[8];
        f32x4 a3 = *(const f32x4*)&brA[12];
        f32x4 a4 = *(const f32x4*)&brA[16];
        float m0; MAX20T(m0, a0, a1, a2, a3, a4);
        float beta = __builtin_amdgcn_exp2f((a0own - m0) * LOG2E_);
        int L2 = 0;
        for (int tt = 1; tt < 64; ++tt) {
            if (MBIT(tt)) {
                float pe = pe_lds[tt * NT_ + jc];
                if (act) brA[ln] = beta;
                LGKM0();
                f32x4 b0 = *(const f32x4*)&brA[0];
                f32x4 b1 = *(const f32x4*)&brA[4];
                f32x4 b2 = *(const f32x4*)&brA[8];
                f32x4 b3 = *(const f32x4*)&brA[12];
                f32x4 b4 = *(const f32x4*)&brA[16];
                float mx; MAX20T(mx, b0, b1, b2, b3, b4);
                f32x4 pr = b0 * E0 + b1 * E1 + b2 * E2 + b3 * E3 + b4 * E4;
                float dot = (pr[0] + pr[1]) + (pr[2] + pr[3]);
                unsigned bits; __builtin_memcpy(&bits, &mx, 4);
                int ex = (int)((bits >> 23) & 255u) - 127;
                unsigned rb = (unsigned)(127 - ex) << 23;
                float r; __builtin_memcpy(&r, &rb, 4);
                L2 += ex;
                beta = dot * r * pe;
            }
        }
        if (act) Fv[ln] = beta;
        if (ln == 0) CfL = m0 + (float)L2 * LN2_;
    } else if (w == 1) {
        f32x4 r0, r1, r2, r3, r4;
        #define LDTR(v, q) v = (f32x4){ ttrans[jc*NT_ + 4*(q)+0], ttrans[jc*NT_ + 4*(q)+1], \
                                        ttrans[jc*NT_ + 4*(q)+2], ttrans[jc*NT_ + 4*(q)+3] }
        LDTR(r0, 0); LDTR(r1, 1); LDTR(r2, 2); LDTR(r3, 3); LDTR(r4, 4);
        f32x4 E0, E1, E2, E3, E4;
        EXPC(E0, r0); EXPC(E1, r1); EXPC(E2, r2); EXPC(E3, r3); EXPC(E4, r4);
        f32x4 d0 = (f32x4){ tend[0],  tend[1],  tend[2],  tend[3]  };
        f32x4 d1 = (f32x4){ tend[4],  tend[5],  tend[6],  tend[7]  };
        f32x4 d2 = (f32x4){ tend[8],  tend[9],  tend[10], tend[11] };
        f32x4 d3 = (f32x4){ tend[12], tend[13], tend[14], tend[15] };
        f32x4 d4 = (f32x4){ tend[16], tend[17], tend[18], tend[19] };
        float mend; MAX20T(mend, d0, d1, d2, d3, d4);
        float G = __builtin_amdgcn_exp2f((tend[jc] - mend) * LOG2E_);
        int L2b = 0;
        for (int tt = 126; tt >= 63; --tt) {
            if (MBIT(tt + 1)) {
                float w_own = G * pe_lds[(tt + 1) * NT_ + jc];
                if (act) brB[ln] = w_own;
                LGKM0();
                f32x4 q0 = *(const f32x4*)&brB[0];
                f32x4 q1 = *(const f32x4*)&brB[4];
                f32x4 q2 = *(const f32x4*)&brB[8];
                f32x4 q3 = *(const f32x4*)&brB[12];
                f32x4 q4 = *(const f32x4*)&brB[16];
                float mx; MAX20T(mx, q0, q1, q2, q3, q4);
                f32x4 pr = q0 * E0 + q1 * E1 + q2 * E2 + q3 * E3 + q4 * E4;
                float dot = (pr[0] + pr[1]) + (pr[2] + pr[3]);
                unsigned bits; __builtin_memcpy(&bits, &mx, 4);
                int ex = (int)((bits >> 23) & 255u) - 127;
                unsigned rb = (unsigned)(127 - ex) << 23;
                float r; __builtin_memcpy(&r, &rb, 4);
                L2b += ex;
                G = dot * r;
            }
        }
        if (act) Gv[ln] = G;
        if (ln == 0) CbL = mend + (float)L2b * LN2_;
    } else if (w == 2) {
        f32x4 t0, t1, t2, t3, t4;
        LDTC(t0, 0); LDTC(t1, 1); LDTC(t2, 2); LDTC(t3, 3); LDTC(t4, 4);
        float sown = tstart[jc] + e_lds[jc];
        if (act) brC[ln] = sown;
        LGKM0();
        for (int tt = 1; tt < 64; ++tt) {
            float e = e_lds[tt * NT_ + jc];
            f32x4 a0 = *(const f32x4*)&brC[0];
            f32x4 a1 = *(const f32x4*)&brC[4];
            f32x4 a2 = *(const f32x4*)&brC[8];
            f32x4 a3 = *(const f32x4*)&brC[12];
            f32x4 a4 = *(const f32x4*)&brC[16];
            f32x4 v0 = a0 + t0, v1 = a1 + t1, v2 = a2 + t2, v3 = a3 + t3, v4 = a4 + t4;
            float best; int bi;
            ARGMAX20(best, bi, v0, v1, v2, v3, v4);
            bool m = MBIT(tt);
            float nxt = best + e;
            sown = m ? nxt : sown;
            if (act) {
                brC[ln] = sown;
                P_lds[tt * NT_ + ln] = m ? bi : ln;
            }
            LGKM0();
        }
        if (act) a63[ln] = sown;
    } else {
        f32x4 r0, r1, r2, r3, r4;
        LDTR(r0, 0); LDTR(r1, 1); LDTR(r2, 2); LDTR(r3, 3); LDTR(r4, 4);
        float gown = tend[jc];
        if (act) brD[ln] = gown + e_lds[127 * NT_ + jc];
        LGKM0();
        for (int tt = 126; tt >= 63; --tt) {
            f32x4 q0 = *(const f32x4*)&brD[0];
            f32x4 q1 = *(const f32x4*)&brD[4];
            f32x4 q2 = *(const f32x4*)&brD[8];
            f32x4 q3 = *(const f32x4*)&brD[12];
            f32x4 q4 = *(const f32x4*)&brD[16];
            f32x4 v0 = r0 + q0, v1 = r1 + q1, v2 = r2 + q2, v3 = r3 + q3, v4 = r4 + q4;
            float best; int bi;
            ARGMAX20(best, bi, v0, v1, v2, v3, v4);
            bool m = MBIT(tt + 1);
            gown = m ? best : gown;
            if (act) {
                P_lds[(tt + 1) * NT_ + ln] = m ? bi : ln;
                brD[ln] = gown + e_lds[tt * NT_ + jc];
            }
            LGKM0();
        }
        if (act) g63[ln] = gown;
    }
    __syncthreads();

    if (t == 0) {
        float zf = 0.f;
        #pragma unroll
        for (int j = 0; j < NT_; ++j) zf += Fv[j] * Gv[j];
        float logz = CfL + CbL + __builtin_amdgcn_logf(zf) * LN2_;
        int cnt = __popcll(mlo) + __popcll(mhi);
        float num = part + tend[tags[(cnt - 1) * B_ + b]];
        nll[b] = logz - num;
        float bv = a63[0] + g63[0]; int bt = 0;
        #pragma unroll
        for (int j = 1; j < NT_; ++j) {
            float v = a63[j] + g63[j];
            if (v > bv) { bv = v; bt = j; }
        }
        tag63L = bt;
    }
    __syncthreads();

    if (t == 128) {
        int tag = tag63L;
        out[63 * B_ + b] = (float)tag;
        for (int tt = 63; tt >= 1; --tt) {
            tag = P_lds[tt * NT_ + tag];
            out[(tt - 1) * B_ + b] = (float)tag;
        }
    }
    if (t == 192) {
        int tag = tag63L;
        for (int tt = 64; tt < 128; ++tt) {
            tag = P_lds[tt * NT_ + tag];
            out[tt * B_ + b] = (float)tag;
        }
    }
}

// ---------------- K7: final loss reduce ------------------------------------
__global__ void k_loss(const float* __restrict__ nll, float* __restrict__ out) {
    float v = nll[threadIdx.x];
    #pragma unroll
    for (int o = 32; o >= 1; o >>= 1) v += __shfl_down(v, o);
    if (threadIdx.x == 0) out[S_ * B_] = v;
}

extern "C" void kernel_launch(void* const* d_in, const int* in_sizes, int n_in,
                              void* d_out, int out_size, void* d_ws, size_t ws_size,
                              hipStream_t stream) {
    (void)in_sizes; (void)n_in; (void)out_size; (void)ws_size;
    const int*   words     = (const int*)d_in[0];
    const int*   chars     = (const int*)d_in[1];
    const int*   tags      = (const int*)d_in[2];
    const float* word_emb  = (const float*)d_in[3];
    const float* char_emb  = (const float*)d_in[4];
    const float* ccw       = (const float*)d_in[5];
    const float* ccb       = (const float*)d_in[6];
    const float* lin_w     = (const float*)d_in[7];
    const float* lin_b     = (const float*)d_in[8];
    const float* conv_w    = (const float*)d_in[9];
    const float* conv_b    = (const float*)d_in[10];
    const float* fc_w      = (const float*)d_in[11];
    const float* fc_b      = (const float*)d_in[12];
    const float* crf_start = (const float*)d_in[13];
    const float* crf_end   = (const float*)d_in[14];
    const float* crf_trans = (const float*)d_in[15];

    float* ws   = (float*)d_ws;
    float* em   = ws + EM_OFF;
    float* nll  = ws + NLL_OFF;
    ushort_t* h0  = (ushort_t*)(ws + H0_OFF);
    ushort_t* h1  = (ushort_t*)(ws + H1_OFF);
    ushort_t* wsp = (ushort_t*)(ws + WS_OFF);
    ushort_t* lwp = (ushort_t*)(ws + LW_OFF);
    ushort_t* fsp = (ushort_t*)(ws + FS_OFF);
    float* fwT  = ws + FW_OFF;
    float* out  = (float*)d_out;

    k_word_gather<<<S_ * B_, 128, 0, stream>>>(words, word_emb, fsp);
    k_char_cnn<<<B_ * S_, 128, 0, stream>>>(chars, char_emb, ccw, ccb, fsp);
    k_split_w<<<18432, 256, 0, stream>>>(conv_w, wsp);
    k_split_lw<<<KL_, 512, 0, stream>>>(lin_w, lwp);
    k_split_fw<<<40, 256, 0, stream>>>(fc_w, fwT);
    k_lin_gemm<<<256, 256, 0, stream>>>(lwp, fsp, lin_b, h0);
    k_zero_pad<<<dim3(64, 2), 256, 0, stream>>>(h0, h1);

    k_conv_gemm<<<512, 256, 0, stream>>>(wsp,              h0, conv_b,        h1);
    k_conv_gemm<<<512, 256, 0, stream>>>(wsp + WLAYER,     h1, conv_b + 1024, h0);
    k_conv_gemm<<<512, 256, 0, stream>>>(wsp + 2*WLAYER,   h0, conv_b + 2048, h1);

    k_emis3<<<dim3(8, B_), 256, 0, stream>>>(h1, fwT, fc_b, em);
    k_crf<<<B_, 256, 0, stream>>>(em, words, tags, crf_start, crf_end, crf_trans, nll, out);
    k_loss<<<1, 64, 0, stream>>>(nll, out);
}

// Round 15
// 173.527 us; speedup vs baseline: 1.1198x; 1.0670x over previous
//
#include <hip/hip_runtime.h>
#include <math.h>

typedef unsigned short ushort_t;
typedef short bf16x8 __attribute__((ext_vector_type(8)));
typedef float f32x4 __attribute__((ext_vector_type(4)));
typedef unsigned short u16x8 __attribute__((ext_vector_type(8)));

#define S_ 128
#define B_ 64
#define W_ 16
#define CE_ 30
#define FN_ 4
#define WE_ 300
#define FEAT_ 420
#define C_ 512
#define NT_ 20
#define KL_ 448          // padded K for the 420->512 linear

#define LOG2E_ 1.44269504088896340736f
#define LN2_   0.69314718055994530942f

// ---- workspace layout (float units) ----
#define EM_OFF   0                       // 163,840 floats
#define NLL_OFF  163840                  // 64
#define H0_OFF   163968                  // each h buffer: 64*130*512 bf16 = 2,129,920 floats
#define HBUF_F   2129920
#define H1_OFF   (H0_OFF + HBUF_F)
#define WS_OFF   (H1_OFF + HBUF_F)       // conv w bf16: 3*1024*1536 = 2,359,296 floats
#define WSP_F    2359296
#define LW_OFF   (WS_OFF + WSP_F)        // lin_w bf16: 512*448 = 114,688 floats
#define FS_OFF   (LW_OFF + 114688)       // wf bf16: 8192*448 = 1,835,008 floats
#define FW_OFF   (FS_OFF + 1835008)      // fc_w transposed [20][512] fp32 = 10,240 floats
#define WLAYER   (1024*1536)             // ushort elems per layer

__device__ __forceinline__ float b2f(ushort_t h) {
    unsigned u = ((unsigned)h) << 16;
    float f; __builtin_memcpy(&f, &u, 4); return f;
}
__device__ __forceinline__ ushort_t f2b(float f) {   // round-to-nearest-even
    unsigned u; __builtin_memcpy(&u, &f, 4);
    unsigned r = (u + 0x7FFFu + ((u >> 16) & 1u)) >> 16;
    return (ushort_t)r;
}
__device__ __forceinline__ void gload16(const void* g, void* l) {
    __builtin_amdgcn_global_load_lds((const __attribute__((address_space(1))) void*)g,
                                     (__attribute__((address_space(3))) void*)l,
                                     16, 0, 0);
}

// ---------------- K1: fused word-emb gather + char CNN -> fsp bf16 ---------
__global__ void k_embed(const int* __restrict__ words,
                        const float* __restrict__ word_emb,
                        const int* __restrict__ chars,
                        const float* __restrict__ char_emb,
                        const float* __restrict__ cw,
                        const float* __restrict__ cb,
                        ushort_t* __restrict__ Fh) {
    const int n = blockIdx.x;            // 0..8191
    const int t = threadIdx.x;           // 128 threads
    // --- word part: n = s*B + b ---
    {
        int s = n >> 6, b = n & 63;
        int np = b * 128 + s;
        int wid = words[n];
        if (t < WE_ / 4) {
            float4 v = ((const float4*)(word_emb + (size_t)wid * WE_))[t];
            ushort4 o;
            o.x = f2b(v.x); o.y = f2b(v.y); o.z = f2b(v.z); o.w = f2b(v.w);
            *(ushort4*)(Fh + (size_t)np * KL_ + t * 4) = o;
        }
    }
    // --- char CNN part: n = b*S + s ---
    {
        int b = n >> 7, s = n & 127;
        int np = b * 128 + s;
        __shared__ int cidx[W_];
        if (t < W_) cidx[t] = chars[n * W_ + t];
        __syncthreads();
        if (t < CE_ * FN_) {
            int g = t >> 2;
            float w0 = cw[t*3+0], w1 = cw[t*3+1], w2 = cw[t*3+2];
            float x[W_];
            #pragma unroll
            for (int j = 0; j < W_; ++j) x[j] = char_emb[cidx[j] * CE_ + g];
            float m = -INFINITY;
            #pragma unroll
            for (int j = 0; j < W_ - 2; ++j) {
                float v = x[j]*w0 + x[j+1]*w1 + x[j+2]*w2;
                m = fmaxf(m, v);
            }
            Fh[(size_t)np * KL_ + WE_ + t] = f2b(m + cb[t]);
        }
        if (t < KL_ - FEAT_) Fh[(size_t)np * KL_ + FEAT_ + t] = 0;   // pad 420..447
    }
}

// ---------------- K2: fused weight prep (conv w, lin w, fc w, h pads) ------
// grid 19624 x 256:
//   [0, 18432)        : conv_w -> bf16, k' = kr*512+ci
//   [18432, 19328)    : lin_w  -> [c=512][k=448] bf16 transposed/padded
//   [19328, 19368)    : fc_w   -> fwT [20][512] fp32
//   [19368, 19624)    : zero pad rows of h0/h1
__global__ void k_prep(const float* __restrict__ conv_w, ushort_t* __restrict__ Wt,
                       const float* __restrict__ lin_w,  ushort_t* __restrict__ Lh,
                       const float* __restrict__ fc_w,   float* __restrict__ fwT,
                       ushort_t* __restrict__ h0, ushort_t* __restrict__ h1) {
    const int bid = blockIdx.x;
    const int t = threadIdx.x;
    if (bid < 18432) {
        size_t i = (size_t)bid * 256 + t;                // 3*1024*1536 total
        int ci = (int)(i & 511);
        int kr = (int)((i >> 9) % 3);
        size_t lo_ = i / 1536;                           // l*1024 + o
        Wt[i] = f2b(conv_w[lo_ * 1536 + (size_t)ci * 3 + kr]);
    } else if (bid < 19328) {
        int idx = (bid - 18432) * 256 + t;               // 512*448
        int c = idx / KL_, k = idx - c * KL_;
        float v = (k < FEAT_) ? lin_w[(size_t)k * C_ + c] : 0.f;
        Lh[idx] = f2b(v);
    } else if (bid < 19368) {
        int idx = (bid - 19328) * 256 + t;               // 10240
        if (idx < NT_ * C_) {
            int j = idx >> 9, c = idx & 511;
            fwT[idx] = fc_w[(size_t)c * NT_ + j];
        }
    } else {
        int r = bid - 19368;                             // 256 rows
        int b = r >> 2, which = r & 3;
        ushort_t* buf = (which & 1) ? h1 : h0;
        int row = (which >> 1) ? 129 : 0;
        ((unsigned*)(buf + ((size_t)b * 130 + row) * 512))[t] = 0u;
    }
}

// ---------------- K3: linear 420->512 as bf16 MFMA GEMM --------------------
__global__ __launch_bounds__(256) void k_lin_gemm(
    const ushort_t* __restrict__ Lh, const ushort_t* __restrict__ Fh,
    const float* __restrict__ lb, ushort_t* __restrict__ Oh)
{
    __shared__ short lds[8192];          // A, B tiles 4096 shorts each
    short* AhS = lds;
    short* BhS = lds + 4096;

    const int bid = blockIdx.x;
    const int c0 = (bid & 3) << 7;
    const int n0 = (bid >> 2) << 7;
    const int t = threadIdx.x;
    const int w = t >> 6;
    const int lane = t & 63;
    const int wr = w >> 1, wc = w & 1;

    const int srow0 = (w << 5) + (lane >> 2);
    const int srow1 = srow0 + 16;
    const int j0 = (lane & 3) ^ ((srow0 >> 1) & 3);
    const int j1 = (lane & 3) ^ ((srow1 >> 1) & 3);
    const size_t aoff0 = (size_t)(c0 + srow0) * KL_ + j0 * 8;
    const size_t aoff1 = (size_t)(c0 + srow1) * KL_ + j1 * 8;
    const size_t boff0 = (size_t)(n0 + srow0) * KL_ + j0 * 8;
    const size_t boff1 = (size_t)(n0 + srow1) * KL_ + j1 * 8;
    const int wofs = w << 10;

    const int lr = lane & 15, kg = lane >> 4;
    int aro[4], bro[4];
    #pragma unroll
    for (int m = 0; m < 4; ++m) { int r = (wr << 6) + (m << 4) + lr; aro[m] = (r << 5) + ((kg ^ ((r >> 1) & 3)) << 3); }
    #pragma unroll
    for (int n = 0; n < 4; ++n) { int r = (wc << 6) + (n << 4) + lr; bro[n] = (r << 5) + ((kg ^ ((r >> 1) & 3)) << 3); }

    f32x4 acc[4][4];
    #pragma unroll
    for (int m = 0; m < 4; ++m)
        #pragma unroll
        for (int n = 0; n < 4; ++n) acc[m][n] = (f32x4){0.f, 0.f, 0.f, 0.f};

    for (int k0 = 0; k0 < KL_; k0 += 32) {
        gload16(Lh + aoff0 + k0, AhS + wofs);
        gload16(Lh + aoff1 + k0, AhS + wofs + 512);
        gload16(Fh + boff0 + k0, BhS + wofs);
        gload16(Fh + boff1 + k0, BhS + wofs + 512);
        __syncthreads();
        bf16x8 avh[4], bvh[4];
        #pragma unroll
        for (int m = 0; m < 4; ++m) avh[m] = *(const bf16x8*)(AhS + aro[m]);
        #pragma unroll
        for (int n = 0; n < 4; ++n) bvh[n] = *(const bf16x8*)(BhS + bro[n]);
        #pragma unroll
        for (int m = 0; m < 4; ++m)
            #pragma unroll
            for (int n = 0; n < 4; ++n)
                acc[m][n] = __builtin_amdgcn_mfma_f32_16x16x32_bf16(avh[m], bvh[n], acc[m][n], 0, 0, 0);
        __syncthreads();
    }

    #pragma unroll
    for (int m = 0; m < 4; ++m) {
        const int c = c0 + (wr << 6) + (m << 4) + (kg << 2);
        float4 bb = *(const float4*)(lb + c);
        #pragma unroll
        for (int n = 0; n < 4; ++n) {
            const int np = n0 + (wc << 6) + (n << 4) + lr;
            const int b = np >> 7, s = np & 127;
            ushort4 h4;
            h4.x = f2b(acc[m][n][0] + bb.x);
            h4.y = f2b(acc[m][n][1] + bb.y);
            h4.z = f2b(acc[m][n][2] + bb.z);
            h4.w = f2b(acc[m][n][3] + bb.w);
            *(ushort4*)(Oh + ((size_t)b * 130 + s + 1) * 512 + c) = h4;
        }
    }
}

// ---------------- K4: GLU conv layer, batch-pinned XCD mapping -------------
// Grid 512: co = bid>>6 (8 panels), b = bid&63.  bid%8 == b%8, so ALL eight
// co-panel blocks of batch b land on the SAME XCD: h[b] is written and
// re-read within one XCD's L2 across layers (no cross-die H traffic).
// 2-phase double-buffered K-loop (prefetch it+1 before compute of it).
#define CBUFS 16896                      // shorts per buffer: A 3*4096 + B 4608
__global__ __launch_bounds__(256) void k_conv_gemm(
    const ushort_t* __restrict__ Wt, const ushort_t* __restrict__ Ht,
    const float* __restrict__ cb,          // conv_b + l*1024
    ushort_t* __restrict__ Ot)
{
    __shared__ short lds2[2 * CBUFS];      // 67584 B; epilogue g_lds aliases base
    float* g_lds = (float*)lds2;           // 128*68 f32 = 34816 B

    const int bid  = blockIdx.x;
    const int co0  = (bid >> 6) << 6;      // 64 output channels per panel
    const int b    = bid & 63;             // batch; b%8 == bid%8 == XCD
    const int t    = threadIdx.x;
    const int w    = t >> 6;               // wave 0..3
    const int lane = t & 63;
    const int wr   = w >> 1;               // 0: a-rows, 1: g-rows
    const int wc   = w & 1;                // s half

    const int srow0 = (w << 5) + (lane >> 2);
    const int srow1 = srow0 + 16;
    const int j0 = (lane & 3) ^ ((srow0 >> 1) & 3);
    const int j1 = (lane & 3) ^ ((srow1 >> 1) & 3);
    const int coA0 = (srow0 < 64) ? (co0 + srow0) : (512 + co0 + srow0 - 64);
    const int coA1 = (srow1 < 64) ? (co0 + srow1) : (512 + co0 + srow1 - 64);
    const size_t aoff0 = (size_t)coA0 * 1536 + j0 * 8;
    const size_t aoff1 = (size_t)coA1 * 1536 + j1 * 8;
    const int lrow = lane >> 2;
    const int wofs = w << 10;

    const int lr = lane & 15, kg = lane >> 4;
    int aro[4];
    #pragma unroll
    for (int m = 0; m < 4; ++m) { int r = (wr << 6) + (m << 4) + lr; aro[m] = (r << 5) + ((kg ^ ((r >> 1) & 3)) << 3); }
    int bro[3][4];
    #pragma unroll
    for (int kr = 0; kr < 3; ++kr)
        #pragma unroll
        for (int n = 0; n < 4; ++n) {
            int r = (wc << 6) + (n << 4) + lr + kr;
            bro[kr][n] = (r << 5) + ((kg ^ ((r >> 1) & 3)) << 3);
        }

    f32x4 acc[4][4];
    #pragma unroll
    for (int m = 0; m < 4; ++m)
        #pragma unroll
        for (int n = 0; n < 4; ++n) acc[m][n] = (f32x4){0.f, 0.f, 0.f, 0.f};

    // ---- prologue: stage tile 0 into buffer 0 ----
    {
        short* AS = lds2;
        short* BS = lds2 + 12288;
        #pragma unroll
        for (int kr = 0; kr < 3; ++kr) {
            gload16(Wt + aoff0 + kr * 512, AS + kr * 4096 + wofs);
            gload16(Wt + aoff1 + kr * 512, AS + kr * 4096 + wofs + 512);
        }
        for (int i = w; i < 9; i += 4) {
            const int rr = (i << 4) + lrow;
            const int sj = (lane & 3) ^ ((rr >> 1) & 3);
            gload16(Ht + ((size_t)b * 130 + rr) * 512 + sj * 8, BS + (i << 9));
        }
    }
    __syncthreads();

    for (int it = 0; it < 16; ++it) {
        const int cur = it & 1;
        // ---- prefetch tile it+1 into the other buffer ----
        if (it + 1 < 16) {
            const int ci0 = (it + 1) << 5;
            short* ASn = lds2 + (cur ^ 1) * CBUFS;
            short* BSn = ASn + 12288;
            #pragma unroll
            for (int kr = 0; kr < 3; ++kr) {
                gload16(Wt + aoff0 + kr * 512 + ci0, ASn + kr * 4096 + wofs);
                gload16(Wt + aoff1 + kr * 512 + ci0, ASn + kr * 4096 + wofs + 512);
            }
            for (int i = w; i < 9; i += 4) {
                const int rr = (i << 4) + lrow;
                const int sj = (lane & 3) ^ ((rr >> 1) & 3);
                gload16(Ht + ((size_t)b * 130 + rr) * 512 + ci0 + sj * 8, BSn + (i << 9));
            }
        }
        // ---- compute from current buffer ----
        const short* AS = lds2 + cur * CBUFS;
        const short* BS = AS + 12288;
        #pragma unroll
        for (int kr = 0; kr < 3; ++kr) {
            const short* A_h = AS + kr * 4096;
            bf16x8 avh[4], bvh[4];
            #pragma unroll
            for (int m = 0; m < 4; ++m) avh[m] = *(const bf16x8*)(A_h + aro[m]);
            #pragma unroll
            for (int n = 0; n < 4; ++n) bvh[n] = *(const bf16x8*)(BS + bro[kr][n]);
            #pragma unroll
            for (int m = 0; m < 4; ++m)
                #pragma unroll
                for (int n = 0; n < 4; ++n)
                    acc[m][n] = __builtin_amdgcn_mfma_f32_16x16x32_bf16(avh[m], bvh[n], acc[m][n], 0, 0, 0);
        }
        __syncthreads();   // drains vmcnt(0) AFTER compute -> prefetch latency hidden
    }

    // ---- fused GLU epilogue: g-waves hand their acc to a-waves via LDS ----
    const float rs = 0.70710678118654752f;
    if (wr == 1) {
        #pragma unroll
        for (int m = 0; m < 4; ++m) {
            const int co_l = (m << 4) + (kg << 2);
            float4 bg = *(const float4*)(cb + 512 + co0 + co_l);
            #pragma unroll
            for (int n = 0; n < 4; ++n) {
                const int s_l = (wc << 6) + (n << 4) + lr;
                float4 gv;
                gv.x = acc[m][n][0] + bg.x;
                gv.y = acc[m][n][1] + bg.y;
                gv.z = acc[m][n][2] + bg.z;
                gv.w = acc[m][n][3] + bg.w;
                *(float4*)&g_lds[s_l * 68 + co_l] = gv;
            }
        }
    }
    __syncthreads();
    if (wr == 0) {
        #pragma unroll
        for (int m = 0; m < 4; ++m) {
            const int co_l = (m << 4) + (kg << 2);
            float4 ba = *(const float4*)(cb + co0 + co_l);
            #pragma unroll
            for (int n = 0; n < 4; ++n) {
                const int s_l = (wc << 6) + (n << 4) + lr;
                float4 gv = *(const float4*)&g_lds[s_l * 68 + co_l];
                size_t dst = ((size_t)b * 130 + s_l + 1) * 512 + co0 + co_l;
                ushort4 rh = *(const ushort4*)(Ht + dst);
                float a0 = acc[m][n][0] + ba.x, g0 = gv.x;
                float a1 = acc[m][n][1] + ba.y, g1 = gv.y;
                float a2 = acc[m][n][2] + ba.z, g2 = gv.z;
                float a3 = acc[m][n][3] + ba.w, g3 = gv.w;
                ushort4 h4;
                h4.x = f2b((a0 / (1.f + expf(-g0)) + b2f(rh.x)) * rs);
                h4.y = f2b((a1 / (1.f + expf(-g1)) + b2f(rh.y)) * rs);
                h4.z = f2b((a2 / (1.f + expf(-g2)) + b2f(rh.z)) * rs);
                h4.w = f2b((a3 / (1.f + expf(-g3)) + b2f(rh.w)) * rs);
                *(ushort4*)(Ot + dst) = h4;
            }
        }
    }
}

// ---------------- K5: emissions, 512 blocks (b x s-chunk), LDS dot ---------
__global__ __launch_bounds__(256) void k_emis3(const ushort_t* __restrict__ hh,
                                               const float* __restrict__ fwT,  // [20][512]
                                               const float* __restrict__ fc_b,
                                               float* __restrict__ emis) {
    __shared__ short hlds[16 * 520];          // 16 rows, 512 ch (pad 520)
    __shared__ float wlds[20 * 516];          // 20 tags, 512 ch (pad 516)
    const int b  = blockIdx.y;
    const int sc = blockIdx.x;                // s chunk of 16
    const int t  = threadIdx.x;
    const int w  = t >> 6, lane = t & 63;

    #pragma unroll
    for (int i = 0; i < 4; ++i) {
        int r = w * 4 + i;
        gload16(hh + ((size_t)b * 130 + sc * 16 + r + 1) * 512 + lane * 8,
                hlds + r * 520);
    }
    for (int idx = t; idx < 20 * 128; idx += 256) {
        int j = idx >> 7, cq = (idx & 127) << 2;
        *(float4*)&wlds[j * 516 + cq] = *(const float4*)(fwT + j * 512 + cq);
    }
    __syncthreads();

    #pragma unroll
    for (int pass = 0; pass < 2; ++pass) {
        int slot = t + pass * 256;
        if (slot < 16 * NT_) {
            int r = slot / NT_, j = slot - r * NT_;
            const short* hp = hlds + r * 520;
            const float* wp = wlds + j * 516;
            float acc = 0.f;
            for (int c0 = 0; c0 < 512; c0 += 8) {
                u16x8 hv = *(const u16x8*)(hp + c0);
                float4 w0 = *(const float4*)(wp + c0);
                float4 w1 = *(const float4*)(wp + c0 + 4);
                acc += b2f(hv[0])*w0.x + b2f(hv[1])*w0.y + b2f(hv[2])*w0.z + b2f(hv[3])*w0.w
                     + b2f(hv[4])*w1.x + b2f(hv[5])*w1.y + b2f(hv[6])*w1.z + b2f(hv[7])*w1.w;
            }
            int s = sc * 16 + r;
            emis[((size_t)s * B_ + b) * NT_ + j] = acc + fc_b[j];
        }
    }
}

// ---------------- K6: bidirectional CRF, 4 waves ---------------------------
#define VMAX(a, b) __builtin_elementwise_max((a), (b))
#define MAX20T(mx, a0, a1, a2, a3, a4) \
    { f32x4 mv_ = VMAX(VMAX(VMAX(a0, a1), VMAX(a2, a3)), a4); \
      mx = fmaxf(fmaxf(mv_[0], mv_[1]), fmaxf(mv_[2], mv_[3])); }
#define SEL(ov, oi, av, ai, bv2, bi2) \
    { bool g_ = (bv2) > (av); ov = g_ ? (bv2) : (av); oi = g_ ? (bi2) : (ai); }
#define ARGMAX20(best, bi, v0, v1, v2, v3, v4) \
    { float p0v,p1v,p2v,p3v,p4v,p5v,p6v,p7v,p8v,p9v; \
      int   p0i,p1i,p2i,p3i,p4i,p5i,p6i,p7i,p8i,p9i; \
      SEL(p0v,p0i, v0[0],0,  v0[1],1);  SEL(p1v,p1i, v0[2],2,  v0[3],3); \
      SEL(p2v,p2i, v1[0],4,  v1[1],5);  SEL(p3v,p3i, v1[2],6,  v1[3],7); \
      SEL(p4v,p4i, v2[0],8,  v2[1],9);  SEL(p5v,p5i, v2[2],10, v2[3],11); \
      SEL(p6v,p6i, v3[0],12, v3[1],13); SEL(p7v,p7i, v3[2],14, v3[3],15); \
      SEL(p8v,p8i, v4[0],16, v4[1],17); SEL(p9v,p9i, v4[2],18, v4[3],19); \
      float q0v,q1v,q2v,q3v,q4v; int q0i,q1i,q2i,q3i,q4i; \
      SEL(q0v,q0i,p0v,p0i,p1v,p1i); SEL(q1v,q1i,p2v,p2i,p3v,p3i); \
      SEL(q2v,q2i,p4v,p4i,p5v,p5i); SEL(q3v,q3i,p6v,p6i,p7v,p7i); \
      SEL(q4v,q4i,p8v,p8i,p9v,p9i); \
      float r0v,r1v; int r0i,r1i; \
      SEL(r0v,r0i,q0v,q0i,q1v,q1i); SEL(r1v,r1i,q2v,q2i,q3v,q3i); \
      float s0v; int s0i; \
      SEL(s0v,s0i,r0v,r0i,r1v,r1i); \
      SEL(best,bi,s0v,s0i,q4v,q4i); }
#define EXPC(d, s) d[0]=__builtin_amdgcn_exp2f(s[0]*LOG2E_); d[1]=__builtin_amdgcn_exp2f(s[1]*LOG2E_); \
                   d[2]=__builtin_amdgcn_exp2f(s[2]*LOG2E_); d[3]=__builtin_amdgcn_exp2f(s[3]*LOG2E_)
#define LGKM0() asm volatile("s_waitcnt lgkmcnt(0)" ::: "memory")

__global__ __launch_bounds__(256) void k_crf(const float* __restrict__ emis,
                                             const int* __restrict__ words,
                                             const int* __restrict__ tags,
                                             const float* __restrict__ tstart,
                                             const float* __restrict__ tend,
                                             const float* __restrict__ ttrans,
                                             float* __restrict__ nll,
                                             float* __restrict__ out) {
    __shared__ float e_lds[S_ * NT_];          // 10240 B
    __shared__ float pe_lds[S_ * NT_];         // 10240 B  exp(emis)
    __shared__ int   P_lds[S_ * NT_];          // 10240 B  pointers (t=1..127)
    __shared__ float brA[32], brB[32], brC[32], brD[32];
    __shared__ float Fv[NT_], Gv[NT_], a63[NT_], g63[NT_];
    __shared__ float CfL, CbL;
    __shared__ int tag63L;
    const int b = blockIdx.x;
    const int t = threadIdx.x;
    const int w = t >> 6;
    const int ln = t & 63;

    for (int idx = t; idx < S_ * NT_; idx += 256) {
        int tt = idx / NT_, j = idx - tt * NT_;
        float ev = emis[((size_t)tt * B_ + b) * NT_ + j];
        e_lds[idx] = ev;
        pe_lds[idx] = __builtin_amdgcn_exp2f(ev * LOG2E_);
    }
    __syncthreads();

    unsigned long long mlo = __ballot(words[ln * B_ + b] != 0);
    unsigned long long mhi = __ballot(words[(64 + ln) * B_ + b] != 0);
    const bool act = ln < NT_;
    const int jc = act ? ln : 0;
    float part = 0.f;

    #define MBIT(tt) ((((tt) < 64 ? (mlo >> (tt)) : (mhi >> ((tt) - 64))) & 1ull) != 0)

    if (w == 0) {
        for (int tt = ln; tt < S_; tt += 64) {
            int tgc = tags[tt * B_ + b];
            bool m = MBIT(tt);
            if (tt == 0) {
                part += tstart[tgc] + e_lds[tgc];
            } else if (m) {
                int tgp = tags[(tt - 1) * B_ + b];
                part += ttrans[tgp * NT_ + tgc] + e_lds[tt * NT_ + tgc];
            }
        }
        #pragma unroll
        for (int o = 32; o >= 1; o >>= 1) part += __shfl_down(part, o);

        f32x4 t0, t1, t2, t3, t4;
        #define LDTC(v, q) v = (f32x4){ ttrans[(4*(q)+0)*NT_ + jc], ttrans[(4*(q)+1)*NT_ + jc], \
                                        ttrans[(4*(q)+2)*NT_ + jc], ttrans[(4*(q)+3)*NT_ + jc] }
        LDTC(t0, 0); LDTC(t1, 1); LDTC(t2, 2); LDTC(t3, 3); LDTC(t4, 4);
        f32x4 E0, E1, E2, E3, E4;
        EXPC(E0, t0); EXPC(E1, t1); EXPC(E2, t2); EXPC(E3, t3); EXPC(E4, t4);

        float a0own = tstart[jc] + e_lds[jc];
        if (act) brA[ln] = a0own;
        LGKM0();
        f32x4 a0 = *(const f32x4*)&brA[0];
        f32x4 a1 = *(const f32x4*)&brA[4];
        f32x4 a2 = *(const f32x4*)&brA[8];
        f32x4 a3 = *(const f32x4*)&brA[12];
        f32x4 a4 = *(const f32x4*)&brA[16];
        float m0; MAX20T(m0, a0, a1, a2, a3, a4);
        float beta = __builtin_amdgcn_exp2f((a0own - m0) * LOG2E_);
        int L2 = 0;
        for (int tt = 1; tt < 64; ++tt) {
            if (MBIT(tt)) {
                float pe = pe_lds[tt * NT_ + jc];
                if (act) brA[ln] = beta;
                LGKM0();
                f32x4 b0 = *(const f32x4*)&brA[0];
                f32x4 b1 = *(const f32x4*)&brA[4];
                f32x4 b2 = *(const f32x4*)&brA[8];
                f32x4 b3 = *(const f32x4*)&brA[12];
                f32x4 b4 = *(const f32x4*)&brA[16];
                float mx; MAX20T(mx, b0, b1, b2, b3, b4);
                f32x4 pr = b0 * E0 + b1 * E1 + b2 * E2 + b3 * E3 + b4 * E4;
                float dot = (pr[0] + pr[1]) + (pr[2] + pr[3]);
                unsigned bits; __builtin_memcpy(&bits, &mx, 4);
                int ex = (int)((bits >> 23) & 255u) - 127;
                unsigned rb = (unsigned)(127 - ex) << 23;
                float r; __builtin_memcpy(&r, &rb, 4);
                L2 += ex;
                beta = dot * r * pe;
            }
        }
        if (act) Fv[ln] = beta;
        if (ln == 0) CfL = m0 + (float)L2 * LN2_;
    } else if (w == 1) {
        f32x4 r0, r1, r2, r3, r4;
        #define LDTR(v, q) v = (f32x4){ ttrans[jc*NT_ + 4*(q)+0], ttrans[jc*NT_ + 4*(q)+1], \
                                        ttrans[jc*NT_ + 4*(q)+2], ttrans[jc*NT_ + 4*(q)+3] }
        LDTR(r0, 0); LDTR(r1, 1); LDTR(r2, 2); LDTR(r3, 3); LDTR(r4, 4);
        f32x4 E0, E1, E2, E3, E4;
        EXPC(E0, r0); EXPC(E1, r1); EXPC(E2, r2); EXPC(E3, r3); EXPC(E4, r4);
        f32x4 d0 = (f32x4){ tend[0],  tend[1],  tend[2],  tend[3]  };
        f32x4 d1 = (f32x4){ tend[4],  tend[5],  tend[6],  tend[7]  };
        f32x4 d2 = (f32x4){ tend[8],  tend[9],  tend[10], tend[11] };
        f32x4 d3 = (f32x4){ tend[12], tend[13], tend[14], tend[15] };
        f32x4 d4 = (f32x4){ tend[16], tend[17], tend[18], tend[19] };
        float mend; MAX20T(mend, d0, d1, d2, d3, d4);
        float G = __builtin_amdgcn_exp2f((tend[jc] - mend) * LOG2E_);
        int L2b = 0;
        for (int tt = 126; tt >= 63; --tt) {
            if (MBIT(tt + 1)) {
                float w_own = G * pe_lds[(tt + 1) * NT_ + jc];
                if (act) brB[ln] = w_own;
                LGKM0();
                f32x4 q0 = *(const f32x4*)&brB[0];
                f32x4 q1 = *(const f32x4*)&brB[4];
                f32x4 q2 = *(const f32x4*)&brB[8];
                f32x4 q3 = *(const f32x4*)&brB[12];
                f32x4 q4 = *(const f32x4*)&brB[16];
                float mx; MAX20T(mx, q0, q1, q2, q3, q4);
                f32x4 pr = q0 * E0 + q1 * E1 + q2 * E2 + q3 * E3 + q4 * E4;
                float dot = (pr[0] + pr[1]) + (pr[2] + pr[3]);
                unsigned bits; __builtin_memcpy(&bits, &mx, 4);
                int ex = (int)((bits >> 23) & 255u) - 127;
                unsigned rb = (unsigned)(127 - ex) << 23;
                float r; __builtin_memcpy(&r, &rb, 4);
                L2b += ex;
                G = dot * r;
            }
        }
        if (act) Gv[ln] = G;
        if (ln == 0) CbL = mend + (float)L2b * LN2_;
    } else if (w == 2) {
        f32x4 t0, t1, t2, t3, t4;
        LDTC(t0, 0); LDTC(t1, 1); LDTC(t2, 2); LDTC(t3, 3); LDTC(t4, 4);
        float sown = tstart[jc] + e_lds[jc];
        if (act) brC[ln] = sown;
        LGKM0();
        for (int tt = 1; tt < 64; ++tt) {
            float e = e_lds[tt * NT_ + jc];
            f32x4 a0 = *(const f32x4*)&brC[0];
            f32x4 a1 = *(const f32x4*)&brC[4];
            f32x4 a2 = *(const f32x4*)&brC[8];
            f32x4 a3 = *(const f32x4*)&brC[12];
            f32x4 a4 = *(const f32x4*)&brC[16];
            f32x4 v0 = a0 + t0, v1 = a1 + t1, v2 = a2 + t2, v3 = a3 + t3, v4 = a4 + t4;
            float best; int bi;
            ARGMAX20(best, bi, v0, v1, v2, v3, v4);
            bool m = MBIT(tt);
            float nxt = best + e;
            sown = m ? nxt : sown;
            if (act) {
                brC[ln] = sown;
                P_lds[tt * NT_ + ln] = m ? bi : ln;
            }
            LGKM0();
        }
        if (act) a63[ln] = sown;
    } else {
        f32x4 r0, r1, r2, r3, r4;
        LDTR(r0, 0); LDTR(r1, 1); LDTR(r2, 2); LDTR(r3, 3); LDTR(r4, 4);
        float gown = tend[jc];
        if (act) brD[ln] = gown + e_lds[127 * NT_ + jc];
        LGKM0();
        for (int tt = 126; tt >= 63; --tt) {
            f32x4 q0 = *(const f32x4*)&brD[0];
            f32x4 q1 = *(const f32x4*)&brD[4];
            f32x4 q2 = *(const f32x4*)&brD[8];
            f32x4 q3 = *(const f32x4*)&brD[12];
            f32x4 q4 = *(const f32x4*)&brD[16];
            f32x4 v0 = r0 + q0, v1 = r1 + q1, v2 = r2 + q2, v3 = r3 + q3, v4 = r4 + q4;
            float best; int bi;
            ARGMAX20(best, bi, v0, v1, v2, v3, v4);
            bool m = MBIT(tt + 1);
            gown = m ? best : gown;
            if (act) {
                P_lds[(tt + 1) * NT_ + ln] = m ? bi : ln;
                brD[ln] = gown + e_lds[tt * NT_ + jc];
            }
            LGKM0();
        }
        if (act) g63[ln] = gown;
    }
    __syncthreads();

    if (t == 0) {
        float zf = 0.f;
        #pragma unroll
        for (int j = 0; j < NT_; ++j) zf += Fv[j] * Gv[j];
        float logz = CfL + CbL + __builtin_amdgcn_logf(zf) * LN2_;
        int cnt = __popcll(mlo) + __popcll(mhi);
        float num = part + tend[tags[(cnt - 1) * B_ + b]];
        nll[b] = logz - num;
        float bv = a63[0] + g63[0]; int bt = 0;
        #pragma unroll
        for (int j = 1; j < NT_; ++j) {
            float v = a63[j] + g63[j];
            if (v > bv) { bv = v; bt = j; }
        }
        tag63L = bt;
    }
    __syncthreads();

    if (t == 128) {
        int tag = tag63L;
        out[63 * B_ + b] = (float)tag;
        for (int tt = 63; tt >= 1; --tt) {
            tag = P_lds[tt * NT_ + tag];
            out[(tt - 1) * B_ + b] = (float)tag;
        }
    }
    if (t == 192) {
        int tag = tag63L;
        for (int tt = 64; tt < 128; ++tt) {
            tag = P_lds[tt * NT_ + tag];
            out[tt * B_ + b] = (float)tag;
        }
    }
}

// ---------------- K7: final loss reduce ------------------------------------
__global__ void k_loss(const float* __restrict__ nll, float* __restrict__ out) {
    float v = nll[threadIdx.x];
    #pragma unroll
    for (int o = 32; o >= 1; o >>= 1) v += __shfl_down(v, o);
    if (threadIdx.x == 0) out[S_ * B_] = v;
}

extern "C" void kernel_launch(void* const* d_in, const int* in_sizes, int n_in,
                              void* d_out, int out_size, void* d_ws, size_t ws_size,
                              hipStream_t stream) {
    (void)in_sizes; (void)n_in; (void)out_size; (void)ws_size;
    const int*   words     = (const int*)d_in[0];
    const int*   chars     = (const int*)d_in[1];
    const int*   tags      = (const int*)d_in[2];
    const float* word_emb  = (const float*)d_in[3];
    const float* char_emb  = (const float*)d_in[4];
    const float* ccw       = (const float*)d_in[5];
    const float* ccb       = (const float*)d_in[6];
    const float* lin_w     = (const float*)d_in[7];
    const float* lin_b     = (const float*)d_in[8];
    const float* conv_w    = (const float*)d_in[9];
    const float* conv_b    = (const float*)d_in[10];
    const float* fc_w      = (const float*)d_in[11];
    const float* fc_b      = (const float*)d_in[12];
    const float* crf_start = (const float*)d_in[13];
    const float* crf_end   = (const float*)d_in[14];
    const float* crf_trans = (const float*)d_in[15];

    float* ws   = (float*)d_ws;
    float* em   = ws + EM_OFF;
    float* nll  = ws + NLL_OFF;
    ushort_t* h0  = (ushort_t*)(ws + H0_OFF);
    ushort_t* h1  = (ushort_t*)(ws + H1_OFF);
    ushort_t* wsp = (ushort_t*)(ws + WS_OFF);
    ushort_t* lwp = (ushort_t*)(ws + LW_OFF);
    ushort_t* fsp = (ushort_t*)(ws + FS_OFF);
    float* fwT  = ws + FW_OFF;
    float* out  = (float*)d_out;

    k_embed<<<S_ * B_, 128, 0, stream>>>(words, word_emb, chars, char_emb, ccw, ccb, fsp);
    k_prep<<<19624, 256, 0, stream>>>(conv_w, wsp, lin_w, lwp, fc_w, fwT, h0, h1);
    k_lin_gemm<<<256, 256, 0, stream>>>(lwp, fsp, lin_b, h0);

    k_conv_gemm<<<512, 256, 0, stream>>>(wsp,              h0, conv_b,        h1);
    k_conv_gemm<<<512, 256, 0, stream>>>(wsp + WLAYER,     h1, conv_b + 1024, h0);
    k_conv_gemm<<<512, 256, 0, stream>>>(wsp + 2*WLAYER,   h0, conv_b + 2048, h1);

    k_emis3<<<dim3(8, B_), 256, 0, stream>>>(h1, fwT, fc_b, em);
    k_crf<<<B_, 256, 0, stream>>>(em, words, tags, crf_start, crf_end, crf_trans, nll, out);
    k_loss<<<1, 64, 0, stream>>>(nll, out);
}